// Round 1
// baseline (3007.745 us; speedup 1.0000x reference)
//
#include <hip/hip_runtime.h>

#define ALPHA 5.0e-4f

// ---------------------------------------------------------------------------
// Generic fp32 tiled GEMM:  D = alpha * op(A) @ op(B) + beta * Cin
//   op(A): (M,Kd).  TA=0: A[m*lda+k], TA=1: A[k*lda+m]
//   op(B): (Kd,N).  TB=0: B[k*ldb+n], TB=1: B[n*ldb+k]
//   Cin has same layout as D (ldd). Batched via blockIdx.z with strides.
// ---------------------------------------------------------------------------
template<int BM, int BN, int BK, int TM, int TN, bool TA, bool TB>
__global__ __launch_bounds__(256)
void gemm_f32(const float* __restrict__ A, int lda, long long sA,
              const float* __restrict__ B, int ldb, long long sB,
              float* __restrict__ D, int ldd, long long sD,
              const float* __restrict__ Cin, long long sC,
              int M, int N, int Kd, float alpha, float beta)
{
    constexpr int PAD = 4;
    __shared__ float As[BK][BM + PAD];
    __shared__ float Bs[BK][BN + PAD];
    const int bz = blockIdx.z;
    A += (long long)bz * sA;
    B += (long long)bz * sB;
    const int m0 = blockIdx.y * BM, n0 = blockIdx.x * BN;
    const int tid = threadIdx.x;
    constexpr int NT = 256;
    constexpr int XT = BN / TN;   // threads along n
    constexpr int YT = NT / XT;   // threads along m
    static_assert(BM / TM == YT, "tile mapping");
    static_assert((BM * BK) % NT == 0 && (BN * BK) % NT == 0, "load mapping");
    const int tx = tid % XT, ty = tid / XT;

    float acc[TM][TN];
#pragma unroll
    for (int i = 0; i < TM; ++i)
#pragma unroll
        for (int j = 0; j < TN; ++j) acc[i][j] = 0.0f;

    for (int k0 = 0; k0 < Kd; k0 += BK) {
        for (int e = tid; e < BM * BK; e += NT) {
            int m, k;
            if (!TA) { m = e / BK; k = e % BK; }
            else     { k = e / BM; m = e % BM; }
            As[k][m] = TA ? A[(long long)(k0 + k) * lda + (m0 + m)]
                          : A[(long long)(m0 + m) * lda + (k0 + k)];
        }
        for (int e = tid; e < BN * BK; e += NT) {
            int n, k;
            if (!TB) { k = e / BN; n = e % BN; }
            else     { n = e / BK; k = e % BK; }
            Bs[k][n] = TB ? B[(long long)(n0 + n) * ldb + (k0 + k)]
                          : B[(long long)(k0 + k) * ldb + (n0 + n)];
        }
        __syncthreads();
#pragma unroll
        for (int k = 0; k < BK; ++k) {
            float a[TM], bb[TN];
#pragma unroll
            for (int i = 0; i < TM; ++i) a[i] = As[k][ty + i * YT];
#pragma unroll
            for (int j = 0; j < TN; ++j) bb[j] = Bs[k][tx + j * XT];
#pragma unroll
            for (int i = 0; i < TM; ++i)
#pragma unroll
                for (int j = 0; j < TN; ++j)
                    acc[i][j] = fmaf(a[i], bb[j], acc[i][j]);
        }
        __syncthreads();
    }
    const float* Cb = Cin ? (Cin + (long long)bz * sC) : nullptr;
    float* Db = D + (long long)bz * sD;
#pragma unroll
    for (int i = 0; i < TM; ++i) {
        const int m = m0 + ty + i * YT;
#pragma unroll
        for (int j = 0; j < TN; ++j) {
            const int n = n0 + tx + j * XT;
            float v = alpha * acc[i][j];
            if (Cb) v = fmaf(beta, Cb[(long long)m * ldd + n], v);
            Db[(long long)m * ldd + n] = v;
        }
    }
}

// zt[b][s][c] = z_seq[s][b][c] + 0.01*noise[s][b][c]   (B=16,S=256,C=2048)
__global__ __launch_bounds__(256)
void prep_zt_kernel(const float* __restrict__ zs, const float* __restrict__ no,
                    float* __restrict__ zt)
{
    const long long i4 = (long long)blockIdx.x * 256 + threadIdx.x; // 2,097,152 total
    const long long c4 = i4 & 511;        // C/4 = 512
    const long long bs = i4 >> 9;         // b*256 + s
    const long long b = bs >> 8, sI = bs & 255;
    const long long in4 = (sI * 16 + b) * 512 + c4;
    const float4 z = ((const float4*)zs)[in4];
    const float4 n = ((const float4*)no)[in4];
    float4 o;
    o.x = fmaf(0.01f, n.x, z.x);
    o.y = fmaf(0.01f, n.y, z.y);
    o.z = fmaf(0.01f, n.z, z.z);
    o.w = fmaf(0.01f, n.w, z.w);
    ((float4*)zt)[i4] = o;
}

// r = 2*alpha*I - alpha^2*G   (batched, n x n per batch)
__global__ __launch_bounds__(256)
void r_init_kernel(const float* __restrict__ G, float* __restrict__ r, int n, long long total)
{
    const long long i = (long long)blockIdx.x * 256 + threadIdx.x;
    if (i >= total) return;
    const long long nn = (long long)n * n;
    const long long rem = i % nn;
    const int ii = (int)(rem / n), jj = (int)(rem % n);
    r[i] = (ii == jj ? 2.0f * ALPHA : 0.0f) - (ALPHA * ALPHA) * G[i];
}

// w_mean[b] = r3(G3[b]) @ (nmm[b] @ zq[b]) via the vector Ben-Cohen recursion.
// One block per batch, 512 threads, thread r owns row r of G3[b].
__global__ __launch_bounds__(512)
void pinv3_wmean_kernel(const float* __restrict__ G3,
                        const float* __restrict__ nmm,
                        const float* __restrict__ zq,
                        float* __restrict__ wmean)
{
    const int b = blockIdx.x;
    const int r = threadIdx.x;
    __shared__ alignas(16) float zqs[2048];
    __shared__ alignas(16) float xu[512], xv[512], xh[512], xv2[512], xh2[512], xv3[512], xh3[512];
    for (int c = r; c < 2048; c += 512) zqs[c] = zq[b * 2048 + c];
    __syncthreads();
    // u0 = nmm[b] @ zq[b]
    const float* arow = nmm + ((long long)b * 512 + r) * 2048;
    float u = 0.f;
    for (int c = 0; c < 2048; c += 4) {
        float4 a = *(const float4*)(arow + c);
        float4 z = *(const float4*)(zqs + c);
        u += a.x * z.x + a.y * z.y + a.z * z.z + a.w * z.w;
    }
    xu[r] = u;
    __syncthreads();
    const float* grow = G3 + (long long)b * 512 * 512 + (long long)r * 512;
    auto matvec = [&](const float* __restrict__ x) -> float {
        float s = 0.f;
        for (int j = 0; j < 512; j += 4) {
            float4 g = *(const float4*)(grow + j);
            float4 xx = *(const float4*)(x + j);
            s += g.x * xx.x + g.y * xx.y + g.z * xx.z + g.w * xx.w;
        }
        return s;
    };
    const float A2 = ALPHA * ALPHA;
    // g1(x) = 2a*x - a^2*(G x);  g2(x) = 2g1(x) - g1(G g1(x));  g3 likewise.
    float m1 = matvec(xu);
    float a1 = 2.f * ALPHA * u - A2 * m1;            // a1 = g1(u0)
    xv[r] = a1; __syncthreads();
    float h1 = matvec(xv);                           // h1 = G a1
    xh[r] = h1; __syncthreads();
    float m3 = matvec(xh);                           // G h1
    float t1 = 2.f * ALPHA * h1 - A2 * m3;           // t1 = g1(h1)
    float a2 = 2.f * a1 - t1;                        // a2 = g2(u0)
    xv2[r] = a2; __syncthreads();
    float h2 = matvec(xv2);                          // h2 = G a2
    xh2[r] = h2; __syncthreads();
    float m5 = matvec(xh2);                          // G h2
    float b1 = 2.f * ALPHA * h2 - A2 * m5;           // b1 = g1(h2)
    xv3[r] = b1; __syncthreads();
    float h3 = matvec(xv3);                          // h3 = G b1
    xh3[r] = h3; __syncthreads();
    float m7 = matvec(xh3);                          // G h3
    float t2 = 2.f * ALPHA * h3 - A2 * m7;           // t2 = g1(h3)
    float b2 = 2.f * b1 - t2;                        // b2 = g2(h2)
    wmean[b * 512 + r] = 2.f * a2 - b2;              // g3(u0)
}

// z_retrieved[b, c0+t] = sum_k wmean[b,k] * nmm[b,k,c0+t]
__global__ __launch_bounds__(512)
void zret_kernel(const float* __restrict__ nmm, const float* __restrict__ wmean,
                 float* __restrict__ out)
{
    const int b = blockIdx.y;
    const int c0 = blockIdx.x * 512;
    const int t = threadIdx.x;
    __shared__ float wms[512];
    wms[t] = wmean[b * 512 + t];
    __syncthreads();
    const float* base = nmm + (long long)b * 512 * 2048 + c0 + t;
    float acc = 0.f;
    for (int k = 0; k < 512; ++k)
        acc = fmaf(wms[k], base[(long long)k * 2048], acc);
    out[b * 2048 + c0 + t] = acc;
}

// Z_r_kv[b,d] = sum_c zr[b,c] * W[d,c]   (W: 18432 x 2048)
__global__ __launch_bounds__(256)
void zrkv_kernel(const float* __restrict__ W, const float* __restrict__ zr,
                 float* __restrict__ out)
{
    __shared__ float Ws[64][65];
    __shared__ float zrs[16][64];
    const int d0 = blockIdx.x * 64;
    const int t = threadIdx.x;
    const int dl = t % 64, bg = t / 64;
    float acc[4] = {0.f, 0.f, 0.f, 0.f};
    for (int c0 = 0; c0 < 2048; c0 += 64) {
        for (int e = t; e < 64 * 64; e += 256) {
            int rr = e / 64, cc = e % 64;
            Ws[rr][cc] = W[(long long)(d0 + rr) * 2048 + c0 + cc];
        }
        for (int e = t; e < 16 * 64; e += 256) {
            int bb = e / 64, cc = e % 64;
            zrs[bb][cc] = zr[bb * 2048 + c0 + cc];
        }
        __syncthreads();
#pragma unroll 16
        for (int cc = 0; cc < 64; ++cc) {
            float wv = Ws[dl][cc];
#pragma unroll
            for (int j = 0; j < 4; ++j)
                acc[j] = fmaf(wv, zrs[bg * 4 + j][cc], acc[j]);
        }
        __syncthreads();
    }
#pragma unroll
    for (int j = 0; j < 4; ++j)
        out[(long long)(bg * 4 + j) * 18432 + d0 + dl] = acc[j];
}

// dkl_M partial: sum (nmm - mm)^2 / prior_var[k]
__global__ __launch_bounds__(256)
void dkl_m_partial_kernel(const float* __restrict__ nmm, const float* __restrict__ mm,
                          const float* __restrict__ mlv, float* __restrict__ partial)
{
    __shared__ float ipv[512];
    __shared__ float red[256];
    const int t = threadIdx.x;
    for (int k = t; k < 512; k += 256)
        ipv[k] = 1.0f / (expf(mlv[k]) + 1e-6f);
    __syncthreads();
    const long long n4 = (long long)16 * 512 * 2048 / 4;
    float s = 0.f;
    for (long long i = (long long)blockIdx.x * 256 + t; i < n4; i += (long long)gridDim.x * 256) {
        const long long e = i * 4;
        const int k = (int)((e >> 11) & 511);
        const long long mi = e & ((1LL << 20) - 1);
        float4 a = *(const float4*)(nmm + e);
        float4 p = *(const float4*)(mm + mi);
        float d0 = a.x - p.x, d1 = a.y - p.y, d2 = a.z - p.z, d3 = a.w - p.w;
        s += (d0 * d0 + d1 * d1 + d2 * d2 + d3 * d3) * ipv[k];
    }
    red[t] = s; __syncthreads();
    for (int st = 128; st > 0; st >>= 1) { if (t < st) red[t] += red[t + st]; __syncthreads(); }
    if (t == 0) partial[blockIdx.x] = red[0];
}

__global__ __launch_bounds__(256)
void dkl_m_final_kernel(const float* __restrict__ partial, float* __restrict__ out)
{
    __shared__ float red[256];
    const int t = threadIdx.x;
    float s = 0.f;
    for (int i = t; i < 2048; i += 256) s += partial[i];
    red[t] = s; __syncthreads();
    for (int st = 128; st > 0; st >>= 1) { if (t < st) red[t] += red[t + st]; __syncthreads(); }
    if (t == 0) out[0] = red[0] * (1.0f / 16.0f); // t1+t3 = 0 and t4 = 0 exactly
}

__global__ __launch_bounds__(256)
void dkl_w_kernel(const float* __restrict__ wmean, const float* __restrict__ wlv,
                  float* __restrict__ out)
{
    __shared__ float red[256];
    const int t = threadIdx.x;
    float s = 0.f;
    for (int i = t; i < 16 * 512; i += 256) { float v = wmean[i]; s += v * v; }
    red[t] = s; __syncthreads();
    for (int st = 128; st > 0; st >>= 1) { if (t < st) red[t] += red[t + st]; __syncthreads(); }
    if (t == 0) {
        float l = wlv[0];
        out[0] = 0.5f * (red[0] + 8192.0f * (expf(l) - 1.0f - l));
    }
}

extern "C" void kernel_launch(void* const* d_in, const int* in_sizes, int n_in,
                              void* d_out, int out_size, void* d_ws, size_t ws_size,
                              hipStream_t stream)
{
    (void)in_sizes; (void)n_in; (void)out_size; (void)ws_size;
    const float* z_seq   = (const float*)d_in[0]; // (256,16,2048)
    const float* z_query = (const float*)d_in[1]; // (16,2048)
    const float* noise   = (const float*)d_in[2]; // (256,16,2048)
    const float* mm      = (const float*)d_in[3]; // (512,2048)
    const float* mlv     = (const float*)d_in[4]; // (512,)
    const float* wlv     = (const float*)d_in[5]; // (1,)
    const float* WM      = (const float*)d_in[6]; // (18432,2048)
    float* out = (float*)d_out;                   // [zr 32768 | Zrkv 294912 | dkl_M | dkl_w]

    float* ws = (float*)d_ws;
    float* zt   = ws;                  // 8,388,608 floats (B,S,C)
    float* wbuf = ws + 8388608LL;      // 2,097,152 (B,S,K)
    float* nmm  = ws + 10485760LL;     // 16,777,216 (B,K,C)
    float* pool = ws + 27262976LL;     // 4,194,304 phase pool
    float* vecs = ws + 31457280LL;     // small
    // phase 1 (prior pinv, shared across batch)
    float* G1  = pool;                 // 512*512
    float* r1a = pool + 262144;
    float* r1b = pool + 524288;
    float* t1  = pool + 786432;
    float* P1  = pool + 1048576;       // 2048*512
    // phase 2 (w pinv, batched) — aliases phase 1 (dead by then)
    float* G2  = pool;                 // 16*256*256
    float* r2a = pool + 1048576;
    float* r2b = pool + 2097152;
    float* t2  = pool + 3145728;
    float* Qb  = pool + 2097152;       // 16*512*256, aliases r2b/t2 (dead)
    float* G3  = zt;                   // 16*512*512, aliases zt (dead after nmm)
    float* wmean    = vecs;            // 16*512
    float* partials = vecs + 8192;     // 2048

    // 1. z_t = transpose(z_seq) + 0.01*noise
    prep_zt_kernel<<<8192, 256, 0, stream>>>(z_seq, noise, zt);
    // 2. G1 = mm @ mm^T   (512,512,2048) NT
    gemm_f32<64,64,16,4,4,false,true><<<dim3(8,8,1),256,0,stream>>>(
        mm,2048,0, mm,2048,0, G1,512,0, nullptr,0, 512,512,2048, 1.f,0.f);
    // 3. r1 = 2aI - a^2 G1   (Ben-Cohen step 1 closed-form)
    r_init_kernel<<<1024,256,0,stream>>>(G1, r1a, 512, 262144);
    // 4-7. steps 2,3:  r <- 2r - (rG)r
    gemm_f32<64,64,16,4,4,false,false><<<dim3(8,8,1),256,0,stream>>>(
        r1a,512,0, G1,512,0, t1,512,0, nullptr,0, 512,512,512, 1.f,0.f);
    gemm_f32<64,64,16,4,4,false,false><<<dim3(8,8,1),256,0,stream>>>(
        t1,512,0, r1a,512,0, r1b,512,0, r1a,0, 512,512,512, -1.f,2.f);
    gemm_f32<64,64,16,4,4,false,false><<<dim3(8,8,1),256,0,stream>>>(
        r1b,512,0, G1,512,0, t1,512,0, nullptr,0, 512,512,512, 1.f,0.f);
    gemm_f32<64,64,16,4,4,false,false><<<dim3(8,8,1),256,0,stream>>>(
        t1,512,0, r1b,512,0, r1a,512,0, r1b,0, 512,512,512, -1.f,2.f);
    // 8. P1 = mm^T @ r1   (2048,512,512) TN
    gemm_f32<64,64,16,4,4,true,false><<<dim3(8,32,1),256,0,stream>>>(
        mm,2048,0, r1a,512,0, P1,512,0, nullptr,0, 2048,512,512, 1.f,0.f);
    // 9. w = zt @ P1   (4096,512,2048) NN
    gemm_f32<128,128,8,8,8,false,false><<<dim3(4,32,1),256,0,stream>>>(
        zt,2048,0, P1,512,0, wbuf,512,0, nullptr,0, 4096,512,2048, 1.f,0.f);
    // 10. G2[b] = w[b] @ w[b]^T   (256,256,512) NT batched
    gemm_f32<64,64,16,4,4,false,true><<<dim3(4,4,16),256,0,stream>>>(
        wbuf,512,131072, wbuf,512,131072, G2,256,65536, nullptr,0, 256,256,512, 1.f,0.f);
    // 11. r2 init
    r_init_kernel<<<4096,256,0,stream>>>(G2, r2a, 256, 1048576);
    // 12-15. two iterations, batched
    gemm_f32<64,64,16,4,4,false,false><<<dim3(4,4,16),256,0,stream>>>(
        r2a,256,65536, G2,256,65536, t2,256,65536, nullptr,0, 256,256,256, 1.f,0.f);
    gemm_f32<64,64,16,4,4,false,false><<<dim3(4,4,16),256,0,stream>>>(
        t2,256,65536, r2a,256,65536, r2b,256,65536, r2a,65536, 256,256,256, -1.f,2.f);
    gemm_f32<64,64,16,4,4,false,false><<<dim3(4,4,16),256,0,stream>>>(
        r2b,256,65536, G2,256,65536, t2,256,65536, nullptr,0, 256,256,256, 1.f,0.f);
    gemm_f32<64,64,16,4,4,false,false><<<dim3(4,4,16),256,0,stream>>>(
        t2,256,65536, r2b,256,65536, r2a,256,65536, r2b,65536, 256,256,256, -1.f,2.f);
    // 16. Q[b] = w[b]^T @ r2[b]   (512,256,256) TN batched
    gemm_f32<64,64,16,4,4,true,false><<<dim3(4,8,16),256,0,stream>>>(
        wbuf,512,131072, r2a,256,65536, Qb,256,131072, nullptr,0, 512,256,256, 1.f,0.f);
    // 17. nmm[b] = Q[b] @ zt[b]   (512,2048,256) NN batched
    gemm_f32<128,128,8,8,8,false,false><<<dim3(16,4,16),256,0,stream>>>(
        Qb,256,131072, zt,2048,524288, nmm,2048,1048576, nullptr,0, 512,2048,256, 1.f,0.f);
    // 18. G3[b] = nmm[b] @ nmm[b]^T   (512,512,2048) NT batched
    gemm_f32<128,128,8,8,8,false,true><<<dim3(4,4,16),256,0,stream>>>(
        nmm,2048,1048576, nmm,2048,1048576, G3,512,262144, nullptr,0, 512,512,2048, 1.f,0.f);
    // 19. w_mean via vector Ben-Cohen recursion (7 mat-vecs in 512-space)
    pinv3_wmean_kernel<<<16,512,0,stream>>>(G3, nmm, z_query, wmean);
    // 20. z_retrieved
    zret_kernel<<<dim3(4,16),512,0,stream>>>(nmm, wmean, out);
    // 21. Z_r_kv = zr @ W^T
    zrkv_kernel<<<288,256,0,stream>>>(WM, out, out + 32768);
    // 22-23. dkl_M
    dkl_m_partial_kernel<<<2048,256,0,stream>>>(nmm, mm, mlv, partials);
    dkl_m_final_kernel<<<1,256,0,stream>>>(partials, out + 327680);
    // 24. dkl_w
    dkl_w_kernel<<<1,256,0,stream>>>(wmean, wlv, out + 327681);
}

// Round 2
// 950.564 us; speedup vs baseline: 3.1642x; 3.1642x over previous
//
#include <hip/hip_runtime.h>

#define ALPHA 5.0e-4f

typedef short s16x8 __attribute__((ext_vector_type(8)));
typedef unsigned short u16x8 __attribute__((ext_vector_type(8)));
typedef float f32x4 __attribute__((ext_vector_type(4)));

__device__ __forceinline__ unsigned short f2bf(float f) {
    unsigned int u = __builtin_bit_cast(unsigned int, f);
    u += 0x7fffu + ((u >> 16) & 1u);
    return (unsigned short)(u >> 16);
}

__device__ __forceinline__ f32x4 mfma16(s16x8 a, s16x8 b, f32x4 c) {
    return __builtin_amdgcn_mfma_f32_16x16x32_bf16(a, b, c, 0, 0, 0);
}

// ---------------------------------------------------------------------------
// Staging helpers: fp32 global -> bf16 (hi[,lo]) LDS tile [ROWS][64],
// XOR-swizzled: 16B slot s at row r lives at slot (s ^ (r&7)).
// ---------------------------------------------------------------------------
template<int ROWS, bool SPLIT>
__device__ __forceinline__ void stage_kcontig(const float* __restrict__ src, int ld,
                                              unsigned short* __restrict__ lds, int tid)
{
#pragma unroll
    for (int it = 0; it < ROWS * 8 / 256; ++it) {
        const int g = tid + it * 256;
        const int row = g >> 3, s = g & 7;
        const float* p = src + (long long)row * ld + s * 8;
        const float4 x0 = *(const float4*)p;
        const float4 x1 = *(const float4*)(p + 4);
        const float xs[8] = {x0.x, x0.y, x0.z, x0.w, x1.x, x1.y, x1.z, x1.w};
        u16x8 h, l;
#pragma unroll
        for (int j = 0; j < 8; ++j) {
            const unsigned short hh = f2bf(xs[j]);
            h[j] = hh;
            if (SPLIT) {
                const float fh = __builtin_bit_cast(float, (unsigned int)hh << 16);
                l[j] = f2bf(xs[j] - fh);
            }
        }
        const int off = row * 64 + ((s ^ (row & 7)) << 3);
        *(u16x8*)(lds + off) = h;
        if (SPLIT) *(u16x8*)(lds + ROWS * 64 + off) = l;
    }
}

// src is [k][m] row-major (transposed operand); produce LDS [m][64k]
template<int ROWS, bool SPLIT>
__device__ __forceinline__ void stage_kstrided(const float* __restrict__ src, int ld,
                                               unsigned short* __restrict__ lds, int tid)
{
    constexpr int KPT = ROWS * 64 / 256;     // k's per thread (32 or 16)
    const int m = tid % ROWS, kh = tid / ROWS;
    const int kb = kh * KPT;
#pragma unroll
    for (int j8 = 0; j8 < KPT / 8; ++j8) {
        float xs[8];
#pragma unroll
        for (int j = 0; j < 8; ++j)
            xs[j] = src[(long long)(kb + j8 * 8 + j) * ld + m];
        u16x8 h, l;
#pragma unroll
        for (int j = 0; j < 8; ++j) {
            const unsigned short hh = f2bf(xs[j]);
            h[j] = hh;
            if (SPLIT) {
                const float fh = __builtin_bit_cast(float, (unsigned int)hh << 16);
                l[j] = f2bf(xs[j] - fh);
            }
        }
        const int s = (kb >> 3) + j8;
        const int off = m * 64 + ((s ^ (m & 7)) << 3);
        *(u16x8*)(lds + off) = h;
        if (SPLIT) *(u16x8*)(lds + ROWS * 64 + off) = l;
    }
}

// ---------------------------------------------------------------------------
// bf16 MFMA GEMM:  D = alpha * op(A)@op(B) + beta * Cin
//   TA=0: A[m*lda+k]; TA=1: A[k*lda+m].  TB=0: B[k*ldb+n]; TB=1: B[n*ldb+k].
//   SPLIT: hi/lo bf16 decomposition of both operands (3 MFMAs/product) for
//   near-fp32 accuracy. 256 thr = 4 waves (2x2), BK=64.
// ---------------------------------------------------------------------------
template<int BM, int BN, bool TA, bool TB, bool SPLIT>
__global__ __launch_bounds__(256)
void gemm_mfma(const float* __restrict__ A, int lda, long long sA,
               const float* __restrict__ B, int ldb, long long sB,
               float* __restrict__ D, int ldd, long long sD,
               const float* __restrict__ Cin, long long sC,
               float alpha, float beta, int Kd)
{
    constexpr int TWM = BM / 2, TWN = BN / 2;
    constexpr int FM = TWM / 16, FN = TWN / 16;
    __shared__ unsigned short As[(SPLIT ? 2 : 1) * BM * 64];
    __shared__ unsigned short Bs[(SPLIT ? 2 : 1) * BN * 64];

    const int tid = threadIdx.x;
    const int lane = tid & 63, w = tid >> 6;
    const int wm = w >> 1, wn = w & 1;
    const int lrow = lane & 15, lk = lane >> 4;
    const int m0 = blockIdx.y * BM, n0 = blockIdx.x * BN;
    const float* Ab = A + (long long)blockIdx.z * sA;
    const float* Bb = B + (long long)blockIdx.z * sB;

    f32x4 acc[FM][FN];
#pragma unroll
    for (int i = 0; i < FM; ++i)
#pragma unroll
        for (int j = 0; j < FN; ++j) acc[i][j] = (f32x4){0.f, 0.f, 0.f, 0.f};

    for (int k0 = 0; k0 < Kd; k0 += 64) {
        if (!TA) stage_kcontig<BM, SPLIT>(Ab + (long long)m0 * lda + k0, lda, As, tid);
        else     stage_kstrided<BM, SPLIT>(Ab + (long long)k0 * lda + m0, lda, As, tid);
        if (TB)  stage_kcontig<BN, SPLIT>(Bb + (long long)n0 * ldb + k0, ldb, Bs, tid);
        else     stage_kstrided<BN, SPLIT>(Bb + (long long)k0 * ldb + n0, ldb, Bs, tid);
        __syncthreads();
#pragma unroll
        for (int kk = 0; kk < 2; ++kk) {
            s16x8 ah[FM], bh[FN], al[FM], bl[FN];
#pragma unroll
            for (int i = 0; i < FM; ++i) {
                const int row = wm * TWM + i * 16 + lrow;
                const int s = kk * 4 + lk;
                const int off = row * 64 + ((s ^ (row & 7)) << 3);
                ah[i] = *(const s16x8*)(As + off);
                if (SPLIT) al[i] = *(const s16x8*)(As + BM * 64 + off);
            }
#pragma unroll
            for (int j = 0; j < FN; ++j) {
                const int col = wn * TWN + j * 16 + lrow;
                const int s = kk * 4 + lk;
                const int off = col * 64 + ((s ^ (col & 7)) << 3);
                bh[j] = *(const s16x8*)(Bs + off);
                if (SPLIT) bl[j] = *(const s16x8*)(Bs + BN * 64 + off);
            }
#pragma unroll
            for (int i = 0; i < FM; ++i)
#pragma unroll
                for (int j = 0; j < FN; ++j) {
                    acc[i][j] = mfma16(ah[i], bh[j], acc[i][j]);
                    if (SPLIT) {
                        acc[i][j] = mfma16(ah[i], bl[j], acc[i][j]);
                        acc[i][j] = mfma16(al[i], bh[j], acc[i][j]);
                    }
                }
        }
        __syncthreads();
    }

    const float* Cb = Cin ? (Cin + (long long)blockIdx.z * sC) : nullptr;
    float* Db = D + (long long)blockIdx.z * sD;
#pragma unroll
    for (int i = 0; i < FM; ++i)
#pragma unroll
        for (int j = 0; j < FN; ++j) {
            const int col = n0 + wn * TWN + j * 16 + lrow;
#pragma unroll
            for (int r = 0; r < 4; ++r) {
                const int row = m0 + wm * TWM + i * 16 + lk * 4 + r;
                float v = alpha * acc[i][j][r];
                if (Cb) v = fmaf(beta, Cb[(long long)row * ldd + col], v);
                Db[(long long)row * ldd + col] = v;
            }
        }
}

// zt[b][s][c] = z_seq[s][b][c] + 0.01*noise[s][b][c]   (B=16,S=256,C=2048)
__global__ __launch_bounds__(256)
void prep_zt_kernel(const float* __restrict__ zs, const float* __restrict__ no,
                    float* __restrict__ zt)
{
    const long long i4 = (long long)blockIdx.x * 256 + threadIdx.x;
    const long long c4 = i4 & 511;
    const long long bs = i4 >> 9;
    const long long b = bs >> 8, sI = bs & 255;
    const long long in4 = (sI * 16 + b) * 512 + c4;
    const float4 z = ((const float4*)zs)[in4];
    const float4 n = ((const float4*)no)[in4];
    float4 o;
    o.x = fmaf(0.01f, n.x, z.x);
    o.y = fmaf(0.01f, n.y, z.y);
    o.z = fmaf(0.01f, n.z, z.z);
    o.w = fmaf(0.01f, n.w, z.w);
    ((float4*)zt)[i4] = o;
}

// r = 2*alpha*I - alpha^2*G
__global__ __launch_bounds__(256)
void r_init_kernel(const float* __restrict__ G, float* __restrict__ r, int n, long long total)
{
    const long long i = (long long)blockIdx.x * 256 + threadIdx.x;
    if (i >= total) return;
    const long long nn = (long long)n * n;
    const long long rem = i % nn;
    const int ii = (int)(rem / n), jj = (int)(rem % n);
    r[i] = (ii == jj ? 2.0f * ALPHA : 0.0f) - (ALPHA * ALPHA) * G[i];
}

// u[b,r] = dot(nmm[b,r,:], zq[b,:])
__global__ __launch_bounds__(256)
void u_gemv_kernel(const float* __restrict__ nmm, const float* __restrict__ zq,
                   float* __restrict__ u)
{
    const int b = blockIdx.y, rg = blockIdx.x;
    __shared__ float zqs[2048];
    const int tid = threadIdx.x;
    for (int c = tid; c < 2048; c += 256) zqs[c] = zq[b * 2048 + c];
    __syncthreads();
    const int r16 = tid >> 4, c16 = tid & 15;
    const int row = rg * 16 + r16;
    const float* p = nmm + (long long)b * 1048576 + (long long)row * 2048;
    float s = 0.f;
#pragma unroll 4
    for (int t = 0; t < 32; ++t) {
        const int c = (c16 + t * 16) * 4;
        const float4 x = *(const float4*)(p + c);
        const float4 z = *(const float4*)(zqs + c);
        s += x.x * z.x + x.y * z.y + x.z * z.z + x.w * z.w;
    }
    for (int off = 8; off; off >>= 1) s += __shfl_down(s, off, 16);
    if (c16 == 0) u[b * 512 + row] = s;
}

// w_mean[b] = r3(G3[b]) @ u[b] via the vector Ben-Cohen recursion (7 matvecs).
__global__ __launch_bounds__(512)
void pinv3_wmean_kernel(const float* __restrict__ G3, const float* __restrict__ u0,
                        float* __restrict__ wmean)
{
    const int b = blockIdx.x;
    const int r = threadIdx.x;
    __shared__ alignas(16) float xu[512], xv[512], xh[512], xv2[512], xh2[512], xv3[512], xh3[512];
    const float u = u0[b * 512 + r];
    xu[r] = u;
    __syncthreads();
    const float* grow = G3 + (long long)b * 512 * 512 + (long long)r * 512;
    auto matvec = [&](const float* __restrict__ x) -> float {
        float s = 0.f;
        for (int j = 0; j < 512; j += 4) {
            const float4 g = *(const float4*)(grow + j);
            const float4 xx = *(const float4*)(x + j);
            s += g.x * xx.x + g.y * xx.y + g.z * xx.z + g.w * xx.w;
        }
        return s;
    };
    const float A2 = ALPHA * ALPHA;
    const float m1 = matvec(xu);
    const float a1 = 2.f * ALPHA * u - A2 * m1;
    xv[r] = a1; __syncthreads();
    const float h1 = matvec(xv);
    xh[r] = h1; __syncthreads();
    const float m3 = matvec(xh);
    const float t1 = 2.f * ALPHA * h1 - A2 * m3;
    const float a2 = 2.f * a1 - t1;
    xv2[r] = a2; __syncthreads();
    const float h2 = matvec(xv2);
    xh2[r] = h2; __syncthreads();
    const float m5 = matvec(xh2);
    const float b1 = 2.f * ALPHA * h2 - A2 * m5;
    xv3[r] = b1; __syncthreads();
    const float h3 = matvec(xv3);
    xh3[r] = h3; __syncthreads();
    const float m7 = matvec(xh3);
    const float t2 = 2.f * ALPHA * h3 - A2 * m7;
    const float b2 = 2.f * b1 - t2;
    wmean[b * 512 + r] = 2.f * a2 - b2;
}

// z_retrieved[b, c0+t] = sum_k wmean[b,k] * nmm[b,k,c0+t]
__global__ __launch_bounds__(512)
void zret_kernel(const float* __restrict__ nmm, const float* __restrict__ wmean,
                 float* __restrict__ out)
{
    const int b = blockIdx.y;
    const int c0 = blockIdx.x * 512;
    const int t = threadIdx.x;
    __shared__ float wms[512];
    wms[t] = wmean[b * 512 + t];
    __syncthreads();
    const float* base = nmm + (long long)b * 512 * 2048 + c0 + t;
    float acc = 0.f;
    for (int k = 0; k < 512; ++k)
        acc = fmaf(wms[k], base[(long long)k * 2048], acc);
    out[b * 2048 + c0 + t] = acc;
}

// Z_r_kv[b,d] = sum_c zr[b,c] * W[d,c]
__global__ __launch_bounds__(256)
void zrkv_kernel(const float* __restrict__ W, const float* __restrict__ zr,
                 float* __restrict__ out)
{
    __shared__ float Ws[64][65];
    __shared__ float zrs[16][64];
    const int d0 = blockIdx.x * 64;
    const int t = threadIdx.x;
    const int dl = t % 64, bg = t / 64;
    float acc[4] = {0.f, 0.f, 0.f, 0.f};
    for (int c0 = 0; c0 < 2048; c0 += 64) {
        for (int e = t; e < 64 * 64; e += 256) {
            int rr = e / 64, cc = e % 64;
            Ws[rr][cc] = W[(long long)(d0 + rr) * 2048 + c0 + cc];
        }
        for (int e = t; e < 16 * 64; e += 256) {
            int bb = e / 64, cc = e % 64;
            zrs[bb][cc] = zr[bb * 2048 + c0 + cc];
        }
        __syncthreads();
#pragma unroll 16
        for (int cc = 0; cc < 64; ++cc) {
            float wv = Ws[dl][cc];
#pragma unroll
            for (int j = 0; j < 4; ++j)
                acc[j] = fmaf(wv, zrs[bg * 4 + j][cc], acc[j]);
        }
        __syncthreads();
    }
#pragma unroll
    for (int j = 0; j < 4; ++j)
        out[(long long)(bg * 4 + j) * 18432 + d0 + dl] = acc[j];
}

// dkl_M partial: sum (nmm - mm)^2 / prior_var[k]
__global__ __launch_bounds__(256)
void dkl_m_partial_kernel(const float* __restrict__ nmm, const float* __restrict__ mm,
                          const float* __restrict__ mlv, float* __restrict__ partial)
{
    __shared__ float ipv[512];
    __shared__ float red[256];
    const int t = threadIdx.x;
    for (int k = t; k < 512; k += 256)
        ipv[k] = 1.0f / (expf(mlv[k]) + 1e-6f);
    __syncthreads();
    const long long n4 = (long long)16 * 512 * 2048 / 4;
    float s = 0.f;
    for (long long i = (long long)blockIdx.x * 256 + t; i < n4; i += (long long)gridDim.x * 256) {
        const long long e = i * 4;
        const int k = (int)((e >> 11) & 511);
        const long long mi = e & ((1LL << 20) - 1);
        const float4 a = *(const float4*)(nmm + e);
        const float4 p = *(const float4*)(mm + mi);
        const float d0 = a.x - p.x, d1 = a.y - p.y, d2 = a.z - p.z, d3 = a.w - p.w;
        s += (d0 * d0 + d1 * d1 + d2 * d2 + d3 * d3) * ipv[k];
    }
    red[t] = s; __syncthreads();
    for (int st = 128; st > 0; st >>= 1) { if (t < st) red[t] += red[t + st]; __syncthreads(); }
    if (t == 0) partial[blockIdx.x] = red[0];
}

__global__ __launch_bounds__(256)
void dkl_m_final_kernel(const float* __restrict__ partial, float* __restrict__ out)
{
    __shared__ float red[256];
    const int t = threadIdx.x;
    float s = 0.f;
    for (int i = t; i < 2048; i += 256) s += partial[i];
    red[t] = s; __syncthreads();
    for (int st = 128; st > 0; st >>= 1) { if (t < st) red[t] += red[t + st]; __syncthreads(); }
    if (t == 0) out[0] = red[0] * (1.0f / 16.0f);
}

__global__ __launch_bounds__(256)
void dkl_w_kernel(const float* __restrict__ wmean, const float* __restrict__ wlv,
                  float* __restrict__ out)
{
    __shared__ float red[256];
    const int t = threadIdx.x;
    float s = 0.f;
    for (int i = t; i < 16 * 512; i += 256) { float v = wmean[i]; s += v * v; }
    red[t] = s; __syncthreads();
    for (int st = 128; st > 0; st >>= 1) { if (t < st) red[t] += red[t + st]; __syncthreads(); }
    if (t == 0) {
        float l = wlv[0];
        out[0] = 0.5f * (red[0] + 8192.0f * (expf(l) - 1.0f - l));
    }
}

extern "C" void kernel_launch(void* const* d_in, const int* in_sizes, int n_in,
                              void* d_out, int out_size, void* d_ws, size_t ws_size,
                              hipStream_t stream)
{
    (void)in_sizes; (void)n_in; (void)out_size; (void)ws_size;
    const float* z_seq   = (const float*)d_in[0];
    const float* z_query = (const float*)d_in[1];
    const float* noise   = (const float*)d_in[2];
    const float* mm      = (const float*)d_in[3];
    const float* mlv     = (const float*)d_in[4];
    const float* wlv     = (const float*)d_in[5];
    const float* WM      = (const float*)d_in[6];
    float* out = (float*)d_out;

    float* ws = (float*)d_ws;
    float* zt   = ws;                  // (B,S,C) 8,388,608
    float* wbuf = ws + 8388608LL;      // (B,S,K) 2,097,152
    float* nmm  = ws + 10485760LL;     // (B,K,C) 16,777,216
    float* pool = ws + 27262976LL;     // phase pool
    float* vecs = ws + 31457280LL;
    float* G1  = pool;
    float* r1a = pool + 262144;
    float* r1b = pool + 524288;
    float* t1  = pool + 786432;
    float* P1  = pool + 1048576;
    float* G2  = pool;
    float* r2a = pool + 1048576;
    float* r2b = pool + 2097152;
    float* t2  = pool + 3145728;
    float* Qb  = pool + 2097152;
    float* G3  = zt;                   // aliases zt (dead after nmm)
    float* wmean    = vecs;
    float* partials = vecs + 8192;
    float* uvec     = vecs + 16384;

    prep_zt_kernel<<<8192, 256, 0, stream>>>(z_seq, noise, zt);
    // G1 = mm @ mm^T (512,512,2048)
    gemm_mfma<64,64,false,true,true><<<dim3(8,8,1),256,0,stream>>>(
        mm,2048,0, mm,2048,0, G1,512,0, nullptr,0, 1.f,0.f, 2048);
    r_init_kernel<<<1024,256,0,stream>>>(G1, r1a, 512, 262144);
    gemm_mfma<64,64,false,false,true><<<dim3(8,8,1),256,0,stream>>>(
        r1a,512,0, G1,512,0, t1,512,0, nullptr,0, 1.f,0.f, 512);
    gemm_mfma<64,64,false,false,true><<<dim3(8,8,1),256,0,stream>>>(
        t1,512,0, r1a,512,0, r1b,512,0, r1a,0, -1.f,2.f, 512);
    gemm_mfma<64,64,false,false,true><<<dim3(8,8,1),256,0,stream>>>(
        r1b,512,0, G1,512,0, t1,512,0, nullptr,0, 1.f,0.f, 512);
    gemm_mfma<64,64,false,false,true><<<dim3(8,8,1),256,0,stream>>>(
        t1,512,0, r1b,512,0, r1a,512,0, r1b,0, -1.f,2.f, 512);
    // P1 = mm^T @ r1 (2048,512,512)
    gemm_mfma<64,64,true,false,true><<<dim3(8,32,1),256,0,stream>>>(
        mm,2048,0, r1a,512,0, P1,512,0, nullptr,0, 1.f,0.f, 512);
    // w = zt @ P1 (4096,512,2048)
    gemm_mfma<128,64,false,false,false><<<dim3(8,32,1),256,0,stream>>>(
        zt,2048,0, P1,512,0, wbuf,512,0, nullptr,0, 1.f,0.f, 2048);
    // G2[b] = w[b] @ w[b]^T (256,256,512)
    gemm_mfma<64,64,false,true,true><<<dim3(4,4,16),256,0,stream>>>(
        wbuf,512,131072, wbuf,512,131072, G2,256,65536, nullptr,0, 1.f,0.f, 512);
    r_init_kernel<<<4096,256,0,stream>>>(G2, r2a, 256, 1048576);
    gemm_mfma<64,64,false,false,true><<<dim3(4,4,16),256,0,stream>>>(
        r2a,256,65536, G2,256,65536, t2,256,65536, nullptr,0, 1.f,0.f, 256);
    gemm_mfma<64,64,false,false,true><<<dim3(4,4,16),256,0,stream>>>(
        t2,256,65536, r2a,256,65536, r2b,256,65536, r2a,65536, -1.f,2.f, 256);
    gemm_mfma<64,64,false,false,true><<<dim3(4,4,16),256,0,stream>>>(
        r2b,256,65536, G2,256,65536, t2,256,65536, nullptr,0, 1.f,0.f, 256);
    gemm_mfma<64,64,false,false,true><<<dim3(4,4,16),256,0,stream>>>(
        t2,256,65536, r2b,256,65536, r2a,256,65536, r2b,65536, -1.f,2.f, 256);
    // Qb[b] = w[b]^T @ r2[b] (512,256,256)
    gemm_mfma<64,64,true,false,true><<<dim3(4,8,16),256,0,stream>>>(
        wbuf,512,131072, r2a,256,65536, Qb,256,131072, nullptr,0, 1.f,0.f, 256);
    // nmm[b] = Qb[b] @ zt[b] (512,2048,256)
    gemm_mfma<128,128,false,false,false><<<dim3(16,4,16),256,0,stream>>>(
        Qb,256,131072, zt,2048,524288, nmm,2048,1048576, nullptr,0, 1.f,0.f, 256);
    // G3[b] = nmm[b] @ nmm[b]^T (512,512,2048)
    gemm_mfma<128,128,false,true,false><<<dim3(4,4,16),256,0,stream>>>(
        nmm,2048,1048576, nmm,2048,1048576, G3,512,262144, nullptr,0, 1.f,0.f, 2048);
    // u[b] = nmm[b] @ zq[b]
    u_gemv_kernel<<<dim3(32,16),256,0,stream>>>(nmm, z_query, uvec);
    pinv3_wmean_kernel<<<16,512,0,stream>>>(G3, uvec, wmean);
    zret_kernel<<<dim3(4,16),512,0,stream>>>(nmm, wmean, out);
    zrkv_kernel<<<288,256,0,stream>>>(WM, out, out + 32768);
    dkl_m_partial_kernel<<<2048,256,0,stream>>>(nmm, mm, mlv, partials);
    dkl_m_final_kernel<<<1,256,0,stream>>>(partials, out + 327680);
    dkl_w_kernel<<<1,256,0,stream>>>(wmean, wlv, out + 327681);
}

// Round 3
// 576.667 us; speedup vs baseline: 5.2157x; 1.6484x over previous
//
#include <hip/hip_runtime.h>

#define ALPHA 5.0e-4f

typedef short s16x8 __attribute__((ext_vector_type(8)));
typedef unsigned short u16x8 __attribute__((ext_vector_type(8)));
typedef float f32x4 __attribute__((ext_vector_type(4)));
typedef unsigned short ushort_t;

__device__ __forceinline__ unsigned short f2bf(float f) {
    unsigned int u = __builtin_bit_cast(unsigned int, f);
    u += 0x7fffu + ((u >> 16) & 1u);
    return (unsigned short)(u >> 16);
}
__device__ __forceinline__ float bf2f(unsigned short h) {
    return __builtin_bit_cast(float, (unsigned int)h << 16);
}
__device__ __forceinline__ f32x4 mfma16(s16x8 a, s16x8 b, f32x4 c) {
    return __builtin_amdgcn_mfma_f32_16x16x32_bf16(a, b, c, 0, 0, 0);
}

// ---------------------------------------------------------------------------
// Staging helpers -> LDS tile [ROWS][64 bf16], XOR-swizzled (slot ^= row&7).
// ---------------------------------------------------------------------------
template<int ROWS, bool SPLIT>
__device__ __forceinline__ void stage_kcontig(const float* __restrict__ src, int ld,
                                              unsigned short* __restrict__ lds, int tid)
{
#pragma unroll
    for (int it = 0; it < ROWS * 8 / 256; ++it) {
        const int g = tid + it * 256;
        const int row = g >> 3, s = g & 7;
        const float* p = src + (long long)row * ld + s * 8;
        const float4 x0 = *(const float4*)p;
        const float4 x1 = *(const float4*)(p + 4);
        const float xs[8] = {x0.x, x0.y, x0.z, x0.w, x1.x, x1.y, x1.z, x1.w};
        u16x8 h, l;
#pragma unroll
        for (int j = 0; j < 8; ++j) {
            const unsigned short hh = f2bf(xs[j]);
            h[j] = hh;
            if (SPLIT) l[j] = f2bf(xs[j] - bf2f(hh));
        }
        const int off = row * 64 + ((s ^ (row & 7)) << 3);
        *(u16x8*)(lds + off) = h;
        if (SPLIT) *(u16x8*)(lds + ROWS * 64 + off) = l;
    }
}

template<int ROWS, bool SPLIT>
__device__ __forceinline__ void stage_kstrided(const float* __restrict__ src, int ld,
                                               unsigned short* __restrict__ lds, int tid)
{
    constexpr int KPT = ROWS * 64 / 256;
    const int m = tid % ROWS, kb = (tid / ROWS) * KPT;
#pragma unroll
    for (int j8 = 0; j8 < KPT / 8; ++j8) {
        float xs[8];
#pragma unroll
        for (int j = 0; j < 8; ++j)
            xs[j] = src[(long long)(kb + j8 * 8 + j) * ld + m];
        u16x8 h, l;
#pragma unroll
        for (int j = 0; j < 8; ++j) {
            const unsigned short hh = f2bf(xs[j]);
            h[j] = hh;
            if (SPLIT) l[j] = f2bf(xs[j] - bf2f(hh));
        }
        const int s = (kb >> 3) + j8;
        const int off = m * 64 + ((s ^ (m & 7)) << 3);
        *(u16x8*)(lds + off) = h;
        if (SPLIT) *(u16x8*)(lds + ROWS * 64 + off) = l;
    }
}

template<int ROWS>
__device__ __forceinline__ void stage_kcontig_b(const unsigned short* __restrict__ src, int ld,
                                                unsigned short* __restrict__ lds, int tid)
{
#pragma unroll
    for (int it = 0; it < ROWS * 8 / 256; ++it) {
        const int g = tid + it * 256;
        const int row = g >> 3, s = g & 7;
        const u16x8 h = *(const u16x8*)(src + (long long)row * ld + s * 8);
        *(u16x8*)(lds + row * 64 + ((s ^ (row & 7)) << 3)) = h;
    }
}

template<int ROWS>
__device__ __forceinline__ void stage_kstrided_b(const unsigned short* __restrict__ src, int ld,
                                                 unsigned short* __restrict__ lds, int tid)
{
    constexpr int KPT = ROWS * 64 / 256;
    const int m = tid % ROWS, kb = (tid / ROWS) * KPT;
#pragma unroll
    for (int j8 = 0; j8 < KPT / 8; ++j8) {
        u16x8 h;
#pragma unroll
        for (int j = 0; j < 8; ++j)
            h[j] = src[(long long)(kb + j8 * 8 + j) * ld + m];
        const int s = (kb >> 3) + j8;
        *(u16x8*)(lds + m * 64 + ((s ^ (m & 7)) << 3)) = h;
    }
}

// ---------------------------------------------------------------------------
// Unified MFMA GEMM:  D = alpha*op(A)@op(B) + beta*Cin
//   ABF/BBF: operand is bf16 in global.  SPLIT: hi/lo fp32 emulation (f32 only).
//   OBF: D stored bf16.  XSWZ: XCD-aware decode for G3 (grid=(256,1,1), 4x4x16).
// ---------------------------------------------------------------------------
template<int BM, int BN, bool TA, bool TB, bool SPLIT, bool ABF, bool BBF, bool OBF, bool XSWZ>
__global__ __launch_bounds__(256)
void gemm_mfma(const void* __restrict__ Av, int lda, long long sA,
               const void* __restrict__ Bv, int ldb, long long sB,
               void* __restrict__ Dv, int ldd, long long sD,
               const float* __restrict__ Cin, long long sC,
               float alpha, float beta, int Kd)
{
    static_assert(!(SPLIT && (ABF || BBF)), "split only for fp32 operands");
    constexpr int TWM = BM / 2, TWN = BN / 2;
    constexpr int FM = TWM / 16, FN = TWN / 16;
    __shared__ unsigned short As[(SPLIT ? 2 : 1) * BM * 64];
    __shared__ unsigned short Bs[(SPLIT ? 2 : 1) * BN * 64];

    int bx, by, bz;
    if (XSWZ) {  // grid (256): batch -> XCD pinning (batches 2x,2x+1 on xcd x)
        const int lin = blockIdx.x;
        const int xcd = lin & 7, idx = lin >> 3;
        bz = xcd * 2 + (idx & 1);
        const int tile = idx >> 1;
        by = tile >> 2; bx = tile & 3;
    } else { bx = blockIdx.x; by = blockIdx.y; bz = blockIdx.z; }

    const int tid = threadIdx.x;
    const int lane = tid & 63, w = tid >> 6;
    const int wm = w >> 1, wn = w & 1;
    const int lrow = lane & 15, lk = lane >> 4;
    const int m0 = by * BM, n0 = bx * BN;

    f32x4 acc[FM][FN];
#pragma unroll
    for (int i = 0; i < FM; ++i)
#pragma unroll
        for (int j = 0; j < FN; ++j) acc[i][j] = (f32x4){0.f, 0.f, 0.f, 0.f};

    for (int k0 = 0; k0 < Kd; k0 += 64) {
        if (ABF) {
            const unsigned short* Ab = (const unsigned short*)Av + (long long)bz * sA;
            if (!TA) stage_kcontig_b<BM>(Ab + (long long)m0 * lda + k0, lda, As, tid);
            else     stage_kstrided_b<BM>(Ab + (long long)k0 * lda + m0, lda, As, tid);
        } else {
            const float* Ab = (const float*)Av + (long long)bz * sA;
            if (!TA) stage_kcontig<BM, SPLIT>(Ab + (long long)m0 * lda + k0, lda, As, tid);
            else     stage_kstrided<BM, SPLIT>(Ab + (long long)k0 * lda + m0, lda, As, tid);
        }
        if (BBF) {
            const unsigned short* Bb = (const unsigned short*)Bv + (long long)bz * sB;
            if (TB)  stage_kcontig_b<BN>(Bb + (long long)n0 * ldb + k0, ldb, Bs, tid);
            else     stage_kstrided_b<BN>(Bb + (long long)k0 * ldb + n0, ldb, Bs, tid);
        } else {
            const float* Bb = (const float*)Bv + (long long)bz * sB;
            if (TB)  stage_kcontig<BN, SPLIT>(Bb + (long long)n0 * ldb + k0, ldb, Bs, tid);
            else     stage_kstrided<BN, SPLIT>(Bb + (long long)k0 * ldb + n0, ldb, Bs, tid);
        }
        __syncthreads();
#pragma unroll
        for (int kk = 0; kk < 2; ++kk) {
            s16x8 ah[FM], bh[FN], al[FM], bl[FN];
#pragma unroll
            for (int i = 0; i < FM; ++i) {
                const int row = wm * TWM + i * 16 + lrow;
                const int s = kk * 4 + lk;
                const int off = row * 64 + ((s ^ (row & 7)) << 3);
                ah[i] = *(const s16x8*)(As + off);
                if (SPLIT) al[i] = *(const s16x8*)(As + BM * 64 + off);
            }
#pragma unroll
            for (int j = 0; j < FN; ++j) {
                const int col = wn * TWN + j * 16 + lrow;
                const int s = kk * 4 + lk;
                const int off = col * 64 + ((s ^ (col & 7)) << 3);
                bh[j] = *(const s16x8*)(Bs + off);
                if (SPLIT) bl[j] = *(const s16x8*)(Bs + BN * 64 + off);
            }
#pragma unroll
            for (int i = 0; i < FM; ++i)
#pragma unroll
                for (int j = 0; j < FN; ++j) {
                    acc[i][j] = mfma16(ah[i], bh[j], acc[i][j]);
                    if (SPLIT) {
                        acc[i][j] = mfma16(ah[i], bl[j], acc[i][j]);
                        acc[i][j] = mfma16(al[i], bh[j], acc[i][j]);
                    }
                }
        }
        __syncthreads();
    }

    const float* Cb = Cin ? (Cin + (long long)bz * sC) : nullptr;
#pragma unroll
    for (int i = 0; i < FM; ++i)
#pragma unroll
        for (int j = 0; j < FN; ++j) {
            const int col = n0 + wn * TWN + j * 16 + lrow;
#pragma unroll
            for (int r = 0; r < 4; ++r) {
                const int row = m0 + wm * TWM + i * 16 + lk * 4 + r;
                float v = alpha * acc[i][j][r];
                if (Cb) v = fmaf(beta, Cb[(long long)row * ldd + col], v);
                if (OBF) ((unsigned short*)Dv + (long long)bz * sD)[(long long)row * ldd + col] = f2bf(v);
                else     ((float*)Dv + (long long)bz * sD)[(long long)row * ldd + col] = v;
            }
        }
}

// zt_bf16[b][s][c] = bf16(z_seq[s][b][c] + 0.01*noise[s][b][c])
__global__ __launch_bounds__(256)
void prep_zt_kernel(const float* __restrict__ zs, const float* __restrict__ no,
                    unsigned short* __restrict__ ztb)
{
    const long long i8 = (long long)blockIdx.x * 256 + threadIdx.x; // 1,048,576
    const long long c8 = i8 & 255;
    const long long bs = i8 >> 8;          // b*256 + s
    const long long b = bs >> 8, sI = bs & 255;
    const long long in = (sI * 16 + b) * 2048 + c8 * 8;
    const float4 z0 = *(const float4*)(zs + in);
    const float4 z1 = *(const float4*)(zs + in + 4);
    const float4 n0 = *(const float4*)(no + in);
    const float4 n1 = *(const float4*)(no + in + 4);
    u16x8 o;
    o[0] = f2bf(fmaf(0.01f, n0.x, z0.x)); o[1] = f2bf(fmaf(0.01f, n0.y, z0.y));
    o[2] = f2bf(fmaf(0.01f, n0.z, z0.z)); o[3] = f2bf(fmaf(0.01f, n0.w, z0.w));
    o[4] = f2bf(fmaf(0.01f, n1.x, z1.x)); o[5] = f2bf(fmaf(0.01f, n1.y, z1.y));
    o[6] = f2bf(fmaf(0.01f, n1.z, z1.z)); o[7] = f2bf(fmaf(0.01f, n1.w, z1.w));
    *(u16x8*)(ztb + i8 * 8) = o;
}

// r = 2*alpha*I - alpha^2*G
__global__ __launch_bounds__(256)
void r_init_kernel(const float* __restrict__ G, float* __restrict__ r, int n, long long total)
{
    const long long i = (long long)blockIdx.x * 256 + threadIdx.x;
    if (i >= total) return;
    const long long nn = (long long)n * n;
    const long long rem = i % nn;
    const int ii = (int)(rem / n), jj = (int)(rem % n);
    r[i] = (ii == jj ? 2.0f * ALPHA : 0.0f) - (ALPHA * ALPHA) * G[i];
}

// Fused pass over nmm_bf16: u[b,k] = <nmm[b,k,:], zq[b,:]>  and dkl_M partials.
// grid (32 k-tiles, 16 b), 256 thr: thread = (row = t>>4, c16 = t&15)
__global__ __launch_bounds__(256)
void pass1_kernel(const unsigned short* __restrict__ nmmb, const float* __restrict__ zq,
                  const float* __restrict__ mm, const float* __restrict__ mlv,
                  float* __restrict__ u, float* __restrict__ dklpart)
{
    const int b = blockIdx.y, k0 = blockIdx.x * 16;
    const int t = threadIdx.x, row = t >> 4, c16 = t & 15;
    __shared__ float zqs[2048];
    __shared__ float red[256];
    for (int c = t; c < 2048; c += 256) zqs[c] = zq[b * 2048 + c];
    __syncthreads();
    const int k = k0 + row;
    const unsigned short* np = nmmb + (long long)b * 1048576 + (long long)k * 2048;
    const float* mp = mm + (long long)k * 2048;
    float ua = 0.f, da = 0.f;
#pragma unroll 4
    for (int j = 0; j < 16; ++j) {
        const int c = c16 * 8 + j * 128;
        const u16x8 nv = *(const u16x8*)(np + c);
        const float4 m0 = *(const float4*)(mp + c);
        const float4 m1 = *(const float4*)(mp + c + 4);
        const float mf[8] = {m0.x, m0.y, m0.z, m0.w, m1.x, m1.y, m1.z, m1.w};
#pragma unroll
        for (int jj = 0; jj < 8; ++jj) {
            const float nf = bf2f(nv[jj]);
            ua = fmaf(nf, zqs[c + jj], ua);
            const float d = nf - mf[jj];
            da = fmaf(d, d, da);
        }
    }
    for (int off = 8; off; off >>= 1) ua += __shfl_down(ua, off, 16);
    if (c16 == 0) u[b * 512 + k] = ua;
    da *= 1.0f / (expf(mlv[k]) + 1e-6f);
    red[t] = da; __syncthreads();
    for (int st = 128; st > 0; st >>= 1) { if (t < st) red[t] += red[t + st]; __syncthreads(); }
    if (t == 0) dklpart[blockIdx.y * 32 + blockIdx.x] = red[0];
}

__global__ __launch_bounds__(256)
void dkl_m_final_kernel(const float* __restrict__ partial, float* __restrict__ out)
{
    __shared__ float red[256];
    const int t = threadIdx.x;
    float s = 0.f;
    for (int i = t; i < 512; i += 256) s += partial[i];
    red[t] = s; __syncthreads();
    for (int st = 128; st > 0; st >>= 1) { if (t < st) red[t] += red[t + st]; __syncthreads(); }
    if (t == 0) out[0] = red[0] * (1.0f / 16.0f);
}

// w_mean[b] = r3(G3[b]) @ u[b]  (7 matvecs in 512-space; G3 bf16, XCD-matched)
__global__ __launch_bounds__(512)
void pinv3_wmean_kernel(const unsigned short* __restrict__ G3b, const float* __restrict__ u0,
                        float* __restrict__ wmean)
{
    const int bb = (blockIdx.x & 7) * 2 + (blockIdx.x >> 3);  // match G3 XCD placement
    const int r = threadIdx.x;
    __shared__ alignas(16) float xu[512], xv[512], xh[512], xv2[512], xh2[512], xv3[512], xh3[512];
    const float u = u0[bb * 512 + r];
    xu[r] = u;
    __syncthreads();
    const unsigned short* grow = G3b + (long long)bb * 262144 + (long long)r * 512;
    auto matvec = [&](const float* __restrict__ x) -> float {
        float s = 0.f;
#pragma unroll 4
        for (int j = 0; j < 512; j += 8) {
            const u16x8 g = *(const u16x8*)(grow + j);
#pragma unroll
            for (int jj = 0; jj < 8; ++jj) s = fmaf(bf2f(g[jj]), x[j + jj], s);
        }
        return s;
    };
    const float A2 = ALPHA * ALPHA;
    const float m1 = matvec(xu);
    const float a1 = 2.f * ALPHA * u - A2 * m1;
    xv[r] = a1; __syncthreads();
    const float h1 = matvec(xv);
    xh[r] = h1; __syncthreads();
    const float m3 = matvec(xh);
    const float t1 = 2.f * ALPHA * h1 - A2 * m3;
    const float a2 = 2.f * a1 - t1;
    xv2[r] = a2; __syncthreads();
    const float h2 = matvec(xv2);
    xh2[r] = h2; __syncthreads();
    const float m5 = matvec(xh2);
    const float b1 = 2.f * ALPHA * h2 - A2 * m5;
    xv3[r] = b1; __syncthreads();
    const float h3 = matvec(xv3);
    xh3[r] = h3; __syncthreads();
    const float m7 = matvec(xh3);
    const float t2 = 2.f * ALPHA * h3 - A2 * m7;
    const float b2 = 2.f * b1 - t2;
    wmean[bb * 512 + r] = 2.f * a2 - b2;
}

// zret partial over k-range 32: pR[ksp][b][c] = sum_k wmean*nmm
__global__ __launch_bounds__(256)
void zret_part_kernel(const unsigned short* __restrict__ nmmb, const float* __restrict__ wmean,
                      float* __restrict__ pR)
{
    const int b = blockIdx.y, k0 = blockIdx.x * 32, t = threadIdx.x;
    __shared__ float wms[32];
    if (t < 32) wms[t] = wmean[b * 512 + k0 + t];
    __syncthreads();
    const int c = t * 8;
    const unsigned short* np = nmmb + (long long)b * 1048576 + (long long)k0 * 2048 + c;
    float a[8] = {0.f, 0.f, 0.f, 0.f, 0.f, 0.f, 0.f, 0.f};
    for (int k = 0; k < 32; ++k) {
        const u16x8 nv = *(const u16x8*)(np + (long long)k * 2048);
        const float wv = wms[k];
#pragma unroll
        for (int jj = 0; jj < 8; ++jj) a[jj] = fmaf(wv, bf2f(nv[jj]), a[jj]);
    }
    float* o = pR + ((long long)blockIdx.x * 16 + b) * 2048 + c;
    *(float4*)o = (float4){a[0], a[1], a[2], a[3]};
    *(float4*)(o + 4) = (float4){a[4], a[5], a[6], a[7]};
}

// out_zr[b][c] = sum over 16 k-partials
__global__ __launch_bounds__(256)
void zret_combine_kernel(const float* __restrict__ pR, float* __restrict__ out)
{
    const int idx4 = blockIdx.x * 256 + threadIdx.x;   // 8192 float4s
    const int b = idx4 >> 9, c = (idx4 & 511) * 4;
    float4 s = {0.f, 0.f, 0.f, 0.f};
#pragma unroll
    for (int g = 0; g < 16; ++g) {
        const float4 v = *(const float4*)(pR + ((long long)g * 16 + b) * 2048 + c);
        s.x += v.x; s.y += v.y; s.z += v.z; s.w += v.w;
    }
    *(float4*)(out + (long long)b * 2048 + c) = s;
}

// Z_r_kv partials: MFMA streaming over W (M=16 b, N=18432 d, K=2048, Ksplit 4)
__global__ __launch_bounds__(256)
void zrkv_mfma_kernel(const float* __restrict__ W, const float* __restrict__ zr,
                      float* __restrict__ part)
{
    const int tid = threadIdx.x, lane = tid & 63, w = tid >> 6;
    const int d0 = blockIdx.x * 64 + w * 16;
    const int kc0 = blockIdx.y * 512;
    const int rr = lane & 15, kq = lane >> 4;
    // preload A-frags (zr) for 16 K-steps
    s16x8 areg[16];
    const float* zb = zr + rr * 2048 + kc0 + kq * 8;
#pragma unroll
    for (int s = 0; s < 16; ++s) {
        const float4 a0 = *(const float4*)(zb + s * 32);
        const float4 a1 = *(const float4*)(zb + s * 32 + 4);
        u16x8 h;
        h[0] = f2bf(a0.x); h[1] = f2bf(a0.y); h[2] = f2bf(a0.z); h[3] = f2bf(a0.w);
        h[4] = f2bf(a1.x); h[5] = f2bf(a1.y); h[6] = f2bf(a1.z); h[7] = f2bf(a1.w);
        areg[s] = __builtin_bit_cast(s16x8, h);
    }
    f32x4 acc = {0.f, 0.f, 0.f, 0.f};
    const float* wb = W + (long long)(d0 + rr) * 2048 + kc0 + kq * 8;
#pragma unroll 4
    for (int s = 0; s < 16; ++s) {
        const float4 b0 = *(const float4*)(wb + s * 32);
        const float4 b1 = *(const float4*)(wb + s * 32 + 4);
        u16x8 h;
        h[0] = f2bf(b0.x); h[1] = f2bf(b0.y); h[2] = f2bf(b0.z); h[3] = f2bf(b0.w);
        h[4] = f2bf(b1.x); h[5] = f2bf(b1.y); h[6] = f2bf(b1.z); h[7] = f2bf(b1.w);
        acc = mfma16(areg[s], __builtin_bit_cast(s16x8, h), acc);
    }
    // C/D: col(d)=lane&15, row(b)=(lane>>4)*4+r
    float* pb = part + ((long long)blockIdx.y * 16 + kq * 4) * 18432 + d0 + rr;
#pragma unroll
    for (int r = 0; r < 4; ++r) pb[(long long)r * 18432] = acc[r];
}

__global__ __launch_bounds__(256)
void zrkv_combine_kernel(const float* __restrict__ part, float* __restrict__ out)
{
    const int idx4 = blockIdx.x * 256 + threadIdx.x;   // 73728 float4s
    const long long base = (long long)idx4 * 4;
    float4 s = {0.f, 0.f, 0.f, 0.f};
#pragma unroll
    for (int g = 0; g < 4; ++g) {
        const float4 v = *(const float4*)(part + (long long)g * 294912 + base);
        s.x += v.x; s.y += v.y; s.z += v.z; s.w += v.w;
    }
    *(float4*)(out + base) = s;
}

__global__ __launch_bounds__(256)
void dkl_w_kernel(const float* __restrict__ wmean, const float* __restrict__ wlv,
                  float* __restrict__ out)
{
    __shared__ float red[256];
    const int t = threadIdx.x;
    float s = 0.f;
    for (int i = t; i < 16 * 512; i += 256) { float v = wmean[i]; s += v * v; }
    red[t] = s; __syncthreads();
    for (int st = 128; st > 0; st >>= 1) { if (t < st) red[t] += red[t + st]; __syncthreads(); }
    if (t == 0) {
        float l = wlv[0];
        out[0] = 0.5f * (red[0] + 8192.0f * (expf(l) - 1.0f - l));
    }
}

extern "C" void kernel_launch(void* const* d_in, const int* in_sizes, int n_in,
                              void* d_out, int out_size, void* d_ws, size_t ws_size,
                              hipStream_t stream)
{
    (void)in_sizes; (void)n_in; (void)out_size; (void)ws_size;
    const float* z_seq   = (const float*)d_in[0];
    const float* z_query = (const float*)d_in[1];
    const float* noise   = (const float*)d_in[2];
    const float* mm      = (const float*)d_in[3];
    const float* mlv     = (const float*)d_in[4];
    const float* wlv     = (const float*)d_in[5];
    const float* WM      = (const float*)d_in[6];
    float* out = (float*)d_out;   // [zr 32768 | Zrkv 294912 | dkl_M | dkl_w]

    char* wsb = (char*)d_ws;
    unsigned short* ztb  = (unsigned short*)(wsb);                  // 16 MB (B,S,C) bf16
    float*          wbuf = (float*)(wsb + (16LL << 20));            // 8 MB (B,S,K) f32
    unsigned short* nmmb = (unsigned short*)(wsb + (24LL << 20));   // 32 MB (B,K,C) bf16
    unsigned short* G3b  = (unsigned short*)(wsb + (56LL << 20));   // 8 MB (B,K,K) bf16
    float*          pool = (float*)(wsb + (64LL << 20));            // 16 MB phase pool
    float*          pZ   = (float*)(wsb + (80LL << 20));            // 4.5 MB zrkv partials
    float*          pR   = (float*)(wsb + (85LL << 20));            // 2 MB zret partials
    float*          vec  = (float*)(wsb + (87LL << 20));
    float* G1  = pool;
    float* r1a = pool + 262144;
    float* r1b = pool + 524288;
    float* t1  = pool + 786432;
    float* P1  = pool + 1048576;
    float* G2  = pool;
    float* r2a = pool + 1048576;
    float* r2b = pool + 2097152;
    float* t2  = pool + 3145728;
    float* Qb  = pool + 2097152;   // aliases r2b/t2 (dead when written)
    float* wmean    = vec;
    float* uvec     = vec + 8192;
    float* dklpart  = vec + 16384;

    prep_zt_kernel<<<4096, 256, 0, stream>>>(z_seq, noise, ztb);
    // G1 = mm @ mm^T (fp32 split)
    gemm_mfma<64,64,false,true,true,false,false,false,false><<<dim3(8,8,1),256,0,stream>>>(
        mm,2048,0, mm,2048,0, G1,512,0, nullptr,0, 1.f,0.f, 2048);
    r_init_kernel<<<1024,256,0,stream>>>(G1, r1a, 512, 262144);
    gemm_mfma<64,64,false,false,true,false,false,false,false><<<dim3(8,8,1),256,0,stream>>>(
        r1a,512,0, G1,512,0, t1,512,0, nullptr,0, 1.f,0.f, 512);
    gemm_mfma<64,64,false,false,true,false,false,false,false><<<dim3(8,8,1),256,0,stream>>>(
        t1,512,0, r1a,512,0, r1b,512,0, r1a,0, -1.f,2.f, 512);
    gemm_mfma<64,64,false,false,true,false,false,false,false><<<dim3(8,8,1),256,0,stream>>>(
        r1b,512,0, G1,512,0, t1,512,0, nullptr,0, 1.f,0.f, 512);
    gemm_mfma<64,64,false,false,true,false,false,false,false><<<dim3(8,8,1),256,0,stream>>>(
        t1,512,0, r1b,512,0, r1a,512,0, r1b,0, -1.f,2.f, 512);
    // P1 = mm^T @ r1 (2048,512,512)
    gemm_mfma<64,64,true,false,true,false,false,false,false><<<dim3(8,32,1),256,0,stream>>>(
        mm,2048,0, r1a,512,0, P1,512,0, nullptr,0, 1.f,0.f, 512);
    // w = zt_bf16 @ P1 (4096,512,2048)
    gemm_mfma<128,64,false,false,false,true,false,false,false><<<dim3(8,32,1),256,0,stream>>>(
        ztb,2048,0, P1,512,0, wbuf,512,0, nullptr,0, 1.f,0.f, 2048);
    // G2[b] = w[b] @ w[b]^T (fp32 split, batched)
    gemm_mfma<64,64,false,true,true,false,false,false,false><<<dim3(4,4,16),256,0,stream>>>(
        wbuf,512,131072, wbuf,512,131072, G2,256,65536, nullptr,0, 1.f,0.f, 512);
    r_init_kernel<<<4096,256,0,stream>>>(G2, r2a, 256, 1048576);
    gemm_mfma<64,64,false,false,true,false,false,false,false><<<dim3(4,4,16),256,0,stream>>>(
        r2a,256,65536, G2,256,65536, t2,256,65536, nullptr,0, 1.f,0.f, 256);
    gemm_mfma<64,64,false,false,true,false,false,false,false><<<dim3(4,4,16),256,0,stream>>>(
        t2,256,65536, r2a,256,65536, r2b,256,65536, r2a,65536, -1.f,2.f, 256);
    gemm_mfma<64,64,false,false,true,false,false,false,false><<<dim3(4,4,16),256,0,stream>>>(
        r2b,256,65536, G2,256,65536, t2,256,65536, nullptr,0, 1.f,0.f, 256);
    gemm_mfma<64,64,false,false,true,false,false,false,false><<<dim3(4,4,16),256,0,stream>>>(
        t2,256,65536, r2b,256,65536, r2a,256,65536, r2b,65536, -1.f,2.f, 256);
    // Qb[b] = w[b]^T @ r2[b] (512,256,256)
    gemm_mfma<64,64,true,false,true,false,false,false,false><<<dim3(4,8,16),256,0,stream>>>(
        wbuf,512,131072, r2a,256,65536, Qb,256,131072, nullptr,0, 1.f,0.f, 256);
    // nmm[b] = Qb[b] @ zt[b] -> bf16 (512,2048,256)
    gemm_mfma<128,128,false,false,false,false,true,true,false><<<dim3(16,4,16),256,0,stream>>>(
        Qb,256,131072, ztb,2048,524288, nmmb,2048,1048576, nullptr,0, 1.f,0.f, 256);
    // G3[b] = nmm[b] @ nmm[b]^T -> bf16, XCD-pinned (512,512,2048)
    gemm_mfma<128,128,false,true,false,true,true,true,true><<<dim3(256,1,1),256,0,stream>>>(
        nmmb,2048,1048576, nmmb,2048,1048576, G3b,512,262144, nullptr,0, 1.f,0.f, 2048);
    // fused u + dkl_M partials
    pass1_kernel<<<dim3(32,16),256,0,stream>>>(nmmb, z_query, mm, mlv, uvec, dklpart);
    pinv3_wmean_kernel<<<16,512,0,stream>>>(G3b, uvec, wmean);
    zret_part_kernel<<<dim3(16,16),256,0,stream>>>(nmmb, wmean, pR);
    zret_combine_kernel<<<32,256,0,stream>>>(pR, out);
    zrkv_mfma_kernel<<<dim3(288,4),256,0,stream>>>(WM, out, pZ);
    zrkv_combine_kernel<<<288,256,0,stream>>>(pZ, out + 32768);
    dkl_m_final_kernel<<<1,256,0,stream>>>(dklpart, out + 327680);
    dkl_w_kernel<<<1,256,0,stream>>>(wmean, wlv, out + 327681);
}

// Round 4
// 454.050 us; speedup vs baseline: 6.6243x; 1.2701x over previous
//
#include <hip/hip_runtime.h>

#define ALPHA 5.0e-4f

typedef short s16x8 __attribute__((ext_vector_type(8)));
typedef unsigned short u16x8 __attribute__((ext_vector_type(8)));
typedef float f32x4 __attribute__((ext_vector_type(4)));

__device__ __forceinline__ unsigned short f2bf(float f) {
    unsigned int u = __builtin_bit_cast(unsigned int, f);
    u += 0x7fffu + ((u >> 16) & 1u);
    return (unsigned short)(u >> 16);
}
__device__ __forceinline__ float bf2f(unsigned short h) {
    return __builtin_bit_cast(float, (unsigned int)h << 16);
}
__device__ __forceinline__ f32x4 mfma16(s16x8 a, s16x8 b, f32x4 c) {
    return __builtin_amdgcn_mfma_f32_16x16x32_bf16(a, b, c, 0, 0, 0);
}

// ---------------------------------------------------------------------------
// Staging helpers -> LDS tile [ROWS][64 bf16], XOR-swizzled (slot ^= row&7).
// ---------------------------------------------------------------------------
template<int ROWS, bool SPLIT>
__device__ __forceinline__ void stage_kcontig(const float* __restrict__ src, int ld,
                                              unsigned short* __restrict__ lds, int tid)
{
#pragma unroll
    for (int it = 0; it < ROWS * 8 / 256; ++it) {
        const int g = tid + it * 256;
        const int row = g >> 3, s = g & 7;
        const float* p = src + (long long)row * ld + s * 8;
        const float4 x0 = *(const float4*)p;
        const float4 x1 = *(const float4*)(p + 4);
        const float xs[8] = {x0.x, x0.y, x0.z, x0.w, x1.x, x1.y, x1.z, x1.w};
        u16x8 h, l;
#pragma unroll
        for (int j = 0; j < 8; ++j) {
            const unsigned short hh = f2bf(xs[j]);
            h[j] = hh;
            if (SPLIT) l[j] = f2bf(xs[j] - bf2f(hh));
        }
        const int off = row * 64 + ((s ^ (row & 7)) << 3);
        *(u16x8*)(lds + off) = h;
        if (SPLIT) *(u16x8*)(lds + ROWS * 64 + off) = l;
    }
}

template<int ROWS, bool SPLIT>
__device__ __forceinline__ void stage_kstrided(const float* __restrict__ src, int ld,
                                               unsigned short* __restrict__ lds, int tid)
{
    constexpr int KPT = ROWS * 64 / 256;
    const int m = tid % ROWS, kb = (tid / ROWS) * KPT;
#pragma unroll
    for (int j8 = 0; j8 < KPT / 8; ++j8) {
        float xs[8];
#pragma unroll
        for (int j = 0; j < 8; ++j)
            xs[j] = src[(long long)(kb + j8 * 8 + j) * ld + m];
        u16x8 h, l;
#pragma unroll
        for (int j = 0; j < 8; ++j) {
            const unsigned short hh = f2bf(xs[j]);
            h[j] = hh;
            if (SPLIT) l[j] = f2bf(xs[j] - bf2f(hh));
        }
        const int s = (kb >> 3) + j8;
        const int off = m * 64 + ((s ^ (m & 7)) << 3);
        *(u16x8*)(lds + off) = h;
        if (SPLIT) *(u16x8*)(lds + ROWS * 64 + off) = l;
    }
}

template<int ROWS>
__device__ __forceinline__ void stage_kcontig_b(const unsigned short* __restrict__ src, int ld,
                                                unsigned short* __restrict__ lds, int tid)
{
#pragma unroll
    for (int it = 0; it < ROWS * 8 / 256; ++it) {
        const int g = tid + it * 256;
        const int row = g >> 3, s = g & 7;
        const u16x8 h = *(const u16x8*)(src + (long long)row * ld + s * 8);
        *(u16x8*)(lds + row * 64 + ((s ^ (row & 7)) << 3)) = h;
    }
}

template<int ROWS>
__device__ __forceinline__ void stage_kstrided_b(const unsigned short* __restrict__ src, int ld,
                                                 unsigned short* __restrict__ lds, int tid)
{
    constexpr int KPT = ROWS * 64 / 256;
    const int m = tid % ROWS, kb = (tid / ROWS) * KPT;
#pragma unroll
    for (int j8 = 0; j8 < KPT / 8; ++j8) {
        u16x8 h;
#pragma unroll
        for (int j = 0; j < 8; ++j)
            h[j] = src[(long long)(kb + j8 * 8 + j) * ld + m];
        const int s = (kb >> 3) + j8;
        *(u16x8*)(lds + m * 64 + ((s ^ (m & 7)) << 3)) = h;
    }
}

// ---------------------------------------------------------------------------
// Unified MFMA GEMM:  D = alpha*op(A)@op(B) + beta*Cin
// ---------------------------------------------------------------------------
template<int BM, int BN, bool TA, bool TB, bool SPLIT, bool ABF, bool BBF, bool OBF, bool XSWZ>
__global__ __launch_bounds__(256)
void gemm_mfma(const void* __restrict__ Av, int lda, long long sA,
               const void* __restrict__ Bv, int ldb, long long sB,
               void* __restrict__ Dv, int ldd, long long sD,
               const float* __restrict__ Cin, long long sC,
               float alpha, float beta, int Kd)
{
    static_assert(!(SPLIT && (ABF || BBF)), "split only for fp32 operands");
    constexpr int TWM = BM / 2, TWN = BN / 2;
    constexpr int FM = TWM / 16, FN = TWN / 16;
    __shared__ unsigned short As[(SPLIT ? 2 : 1) * BM * 64];
    __shared__ unsigned short Bs[(SPLIT ? 2 : 1) * BN * 64];

    int bx, by, bz;
    if (XSWZ) {  // grid (256): batch -> XCD pinning (batches 2x,2x+1 on xcd x)
        const int lin = blockIdx.x;
        const int xcd = lin & 7, idx = lin >> 3;
        bz = xcd * 2 + (idx & 1);
        const int tile = idx >> 1;
        by = tile >> 2; bx = tile & 3;
    } else { bx = blockIdx.x; by = blockIdx.y; bz = blockIdx.z; }

    const int tid = threadIdx.x;
    const int lane = tid & 63, w = tid >> 6;
    const int wm = w >> 1, wn = w & 1;
    const int lrow = lane & 15, lk = lane >> 4;
    const int m0 = by * BM, n0 = bx * BN;

    f32x4 acc[FM][FN];
#pragma unroll
    for (int i = 0; i < FM; ++i)
#pragma unroll
        for (int j = 0; j < FN; ++j) acc[i][j] = (f32x4){0.f, 0.f, 0.f, 0.f};

    for (int k0 = 0; k0 < Kd; k0 += 64) {
        if (ABF) {
            const unsigned short* Ab = (const unsigned short*)Av + (long long)bz * sA;
            if (!TA) stage_kcontig_b<BM>(Ab + (long long)m0 * lda + k0, lda, As, tid);
            else     stage_kstrided_b<BM>(Ab + (long long)k0 * lda + m0, lda, As, tid);
        } else {
            const float* Ab = (const float*)Av + (long long)bz * sA;
            if (!TA) stage_kcontig<BM, SPLIT>(Ab + (long long)m0 * lda + k0, lda, As, tid);
            else     stage_kstrided<BM, SPLIT>(Ab + (long long)k0 * lda + m0, lda, As, tid);
        }
        if (BBF) {
            const unsigned short* Bb = (const unsigned short*)Bv + (long long)bz * sB;
            if (TB)  stage_kcontig_b<BN>(Bb + (long long)n0 * ldb + k0, ldb, Bs, tid);
            else     stage_kstrided_b<BN>(Bb + (long long)k0 * ldb + n0, ldb, Bs, tid);
        } else {
            const float* Bb = (const float*)Bv + (long long)bz * sB;
            if (TB)  stage_kcontig<BN, SPLIT>(Bb + (long long)n0 * ldb + k0, ldb, Bs, tid);
            else     stage_kstrided<BN, SPLIT>(Bb + (long long)k0 * ldb + n0, ldb, Bs, tid);
        }
        __syncthreads();
#pragma unroll
        for (int kk = 0; kk < 2; ++kk) {
            s16x8 ah[FM], bh[FN], al[FM], bl[FN];
#pragma unroll
            for (int i = 0; i < FM; ++i) {
                const int row = wm * TWM + i * 16 + lrow;
                const int s = kk * 4 + lk;
                const int off = row * 64 + ((s ^ (row & 7)) << 3);
                ah[i] = *(const s16x8*)(As + off);
                if (SPLIT) al[i] = *(const s16x8*)(As + BM * 64 + off);
            }
#pragma unroll
            for (int j = 0; j < FN; ++j) {
                const int col = wn * TWN + j * 16 + lrow;
                const int s = kk * 4 + lk;
                const int off = col * 64 + ((s ^ (col & 7)) << 3);
                bh[j] = *(const s16x8*)(Bs + off);
                if (SPLIT) bl[j] = *(const s16x8*)(Bs + BN * 64 + off);
            }
#pragma unroll
            for (int i = 0; i < FM; ++i)
#pragma unroll
                for (int j = 0; j < FN; ++j) {
                    acc[i][j] = mfma16(ah[i], bh[j], acc[i][j]);
                    if (SPLIT) {
                        acc[i][j] = mfma16(ah[i], bl[j], acc[i][j]);
                        acc[i][j] = mfma16(al[i], bh[j], acc[i][j]);
                    }
                }
        }
        __syncthreads();
    }

    const float* Cb = Cin ? (Cin + (long long)bz * sC) : nullptr;
#pragma unroll
    for (int i = 0; i < FM; ++i)
#pragma unroll
        for (int j = 0; j < FN; ++j) {
            const int col = n0 + wn * TWN + j * 16 + lrow;
#pragma unroll
            for (int r = 0; r < 4; ++r) {
                const int row = m0 + wm * TWM + i * 16 + lk * 4 + r;
                float v = alpha * acc[i][j][r];
                if (Cb) v = fmaf(beta, Cb[(long long)row * ldd + col], v);
                if (OBF) ((unsigned short*)Dv + (long long)bz * sD)[(long long)row * ldd + col] = f2bf(v);
                else     ((float*)Dv + (long long)bz * sD)[(long long)row * ldd + col] = v;
            }
        }
}

// zt_bf16[b][s][c] = bf16(z_seq[s][b][c] + 0.01*noise[s][b][c])
__global__ __launch_bounds__(256)
void prep_zt_kernel(const float* __restrict__ zs, const float* __restrict__ no,
                    unsigned short* __restrict__ ztb)
{
    const long long i8 = (long long)blockIdx.x * 256 + threadIdx.x;
    const long long c8 = i8 & 255;
    const long long bs = i8 >> 8;
    const long long b = bs >> 8, sI = bs & 255;
    const long long in = (sI * 16 + b) * 2048 + c8 * 8;
    const float4 z0 = *(const float4*)(zs + in);
    const float4 z1 = *(const float4*)(zs + in + 4);
    const float4 n0 = *(const float4*)(no + in);
    const float4 n1 = *(const float4*)(no + in + 4);
    u16x8 o;
    o[0] = f2bf(fmaf(0.01f, n0.x, z0.x)); o[1] = f2bf(fmaf(0.01f, n0.y, z0.y));
    o[2] = f2bf(fmaf(0.01f, n0.z, z0.z)); o[3] = f2bf(fmaf(0.01f, n0.w, z0.w));
    o[4] = f2bf(fmaf(0.01f, n1.x, z1.x)); o[5] = f2bf(fmaf(0.01f, n1.y, z1.y));
    o[6] = f2bf(fmaf(0.01f, n1.z, z1.z)); o[7] = f2bf(fmaf(0.01f, n1.w, z1.w));
    *(u16x8*)(ztb + i8 * 8) = o;
}

// r = 2*alpha*I - alpha^2*G
__global__ __launch_bounds__(256)
void r_init_kernel(const float* __restrict__ G, float* __restrict__ r, int n, long long total)
{
    const long long i = (long long)blockIdx.x * 256 + threadIdx.x;
    if (i >= total) return;
    const long long nn = (long long)n * n;
    const long long rem = i % nn;
    const int ii = (int)(rem / n), jj = (int)(rem % n);
    r[i] = (ii == jj ? 2.0f * ALPHA : 0.0f) - (ALPHA * ALPHA) * G[i];
}

// Fused pass over nmm_bf16: u[b,k] = <nmm[b,k,:], zq[b,:]>  and dkl_M partials.
__global__ __launch_bounds__(256)
void pass1_kernel(const unsigned short* __restrict__ nmmb, const float* __restrict__ zq,
                  const float* __restrict__ mm, const float* __restrict__ mlv,
                  float* __restrict__ u, float* __restrict__ dklpart)
{
    const int b = blockIdx.y, k0 = blockIdx.x * 16;
    const int t = threadIdx.x, row = t >> 4, c16 = t & 15;
    __shared__ float zqs[2048];
    __shared__ float red[256];
    for (int c = t; c < 2048; c += 256) zqs[c] = zq[b * 2048 + c];
    __syncthreads();
    const int k = k0 + row;
    const unsigned short* np = nmmb + (long long)b * 1048576 + (long long)k * 2048;
    const float* mp = mm + (long long)k * 2048;
    float ua = 0.f, da = 0.f;
#pragma unroll 4
    for (int j = 0; j < 16; ++j) {
        const int c = c16 * 8 + j * 128;
        const u16x8 nv = *(const u16x8*)(np + c);
        const float4 m0 = *(const float4*)(mp + c);
        const float4 m1 = *(const float4*)(mp + c + 4);
        const float mf[8] = {m0.x, m0.y, m0.z, m0.w, m1.x, m1.y, m1.z, m1.w};
#pragma unroll
        for (int jj = 0; jj < 8; ++jj) {
            const float nf = bf2f(nv[jj]);
            ua = fmaf(nf, zqs[c + jj], ua);
            const float d = nf - mf[jj];
            da = fmaf(d, d, da);
        }
    }
    for (int off = 8; off; off >>= 1) ua += __shfl_down(ua, off, 16);
    if (c16 == 0) u[b * 512 + k] = ua;
    da *= 1.0f / (expf(mlv[k]) + 1e-6f);
    red[t] = da; __syncthreads();
    for (int st = 128; st > 0; st >>= 1) { if (t < st) red[t] += red[t + st]; __syncthreads(); }
    if (t == 0) dklpart[blockIdx.y * 32 + blockIdx.x] = red[0];
}

// One Krylov step: y = G3[b] @ vin[b];  vout = y;  wacc (+)= cIn*y (+ c0*vin if init)
__global__ __launch_bounds__(256)
void g3_matvec_kernel(const unsigned short* __restrict__ G3b, const float* __restrict__ vin,
                      float* __restrict__ vout, float* __restrict__ wacc,
                      float cIn, float c0, int init)
{
    const int b = blockIdx.y, k0 = blockIdx.x * 16;
    __shared__ float xs[512];
    const int t = threadIdx.x;
    for (int c = t; c < 512; c += 256) xs[c] = vin[b * 512 + c];
    __syncthreads();
    const int row = t >> 4, l = t & 15;
    const int r = k0 + row;
    const unsigned short* g = G3b + (long long)b * 262144 + (long long)r * 512 + l * 32;
    float s = 0.f;
#pragma unroll
    for (int j = 0; j < 4; ++j) {
        const u16x8 gv = *(const u16x8*)(g + j * 8);
#pragma unroll
        for (int jj = 0; jj < 8; ++jj) s = fmaf(bf2f(gv[jj]), xs[l * 32 + j * 8 + jj], s);
    }
    for (int off = 8; off; off >>= 1) s += __shfl_down(s, off, 16);
    if (l == 0) {
        vout[b * 512 + r] = s;
        if (init) wacc[b * 512 + r] = c0 * xs[r] + cIn * s;
        else      wacc[b * 512 + r] += cIn * s;
    }
}

// zret partial over k-range 32: pR[ksp][b][c] = sum_k wmean*nmm
__global__ __launch_bounds__(256)
void zret_part_kernel(const unsigned short* __restrict__ nmmb, const float* __restrict__ wmean,
                      float* __restrict__ pR)
{
    const int b = blockIdx.y, k0 = blockIdx.x * 32, t = threadIdx.x;
    __shared__ float wms[32];
    if (t < 32) wms[t] = wmean[b * 512 + k0 + t];
    __syncthreads();
    const int c = t * 8;
    const unsigned short* np = nmmb + (long long)b * 1048576 + (long long)k0 * 2048 + c;
    float a[8] = {0.f, 0.f, 0.f, 0.f, 0.f, 0.f, 0.f, 0.f};
    for (int k = 0; k < 32; ++k) {
        const u16x8 nv = *(const u16x8*)(np + (long long)k * 2048);
        const float wv = wms[k];
#pragma unroll
        for (int jj = 0; jj < 8; ++jj) a[jj] = fmaf(wv, bf2f(nv[jj]), a[jj]);
    }
    float* o = pR + ((long long)blockIdx.x * 16 + b) * 2048 + c;
    *(float4*)o = (float4){a[0], a[1], a[2], a[3]};
    *(float4*)(o + 4) = (float4){a[4], a[5], a[6], a[7]};
}

// Fused epilogue: blocks 0..31 zret combine; block 32 dkl_M final; block 33 dkl_w.
__global__ __launch_bounds__(256)
void epilogue_kernel(const float* __restrict__ pR, const float* __restrict__ dklpart,
                     const float* __restrict__ wmean, const float* __restrict__ wlv,
                     float* __restrict__ out)
{
    const int blk = blockIdx.x, t = threadIdx.x;
    if (blk < 32) {
        const int idx4 = blk * 256 + t;
        const int b = idx4 >> 9, c = (idx4 & 511) * 4;
        float4 s = {0.f, 0.f, 0.f, 0.f};
#pragma unroll
        for (int g = 0; g < 16; ++g) {
            const float4 v = *(const float4*)(pR + ((long long)g * 16 + b) * 2048 + c);
            s.x += v.x; s.y += v.y; s.z += v.z; s.w += v.w;
        }
        *(float4*)(out + (long long)b * 2048 + c) = s;
    } else if (blk == 32) {
        __shared__ float red[256];
        float s = 0.f;
        for (int i = t; i < 512; i += 256) s += dklpart[i];
        red[t] = s; __syncthreads();
        for (int st = 128; st > 0; st >>= 1) { if (t < st) red[t] += red[t + st]; __syncthreads(); }
        if (t == 0) out[327680] = red[0] * (1.0f / 16.0f);
    } else {
        __shared__ float red[256];
        float s = 0.f;
        for (int i = t; i < 16 * 512; i += 256) { const float v = wmean[i]; s += v * v; }
        red[t] = s; __syncthreads();
        for (int st = 128; st > 0; st >>= 1) { if (t < st) red[t] += red[t + st]; __syncthreads(); }
        if (t == 0) {
            const float l = wlv[0];
            out[327681] = 0.5f * (red[0] + 8192.0f * (expf(l) - 1.0f - l));
        }
    }
}

// Z_r_kv partials: MFMA streaming over W (M=16 b, N=18432 d, K=2048, Ksplit 4)
__global__ __launch_bounds__(256)
void zrkv_mfma_kernel(const float* __restrict__ W, const float* __restrict__ zr,
                      float* __restrict__ part)
{
    const int tid = threadIdx.x, lane = tid & 63, w = tid >> 6;
    const int d0 = blockIdx.x * 64 + w * 16;
    const int kc0 = blockIdx.y * 512;
    const int rr = lane & 15, kq = lane >> 4;
    s16x8 areg[16];
    const float* zb = zr + rr * 2048 + kc0 + kq * 8;
#pragma unroll
    for (int s = 0; s < 16; ++s) {
        const float4 a0 = *(const float4*)(zb + s * 32);
        const float4 a1 = *(const float4*)(zb + s * 32 + 4);
        u16x8 h;
        h[0] = f2bf(a0.x); h[1] = f2bf(a0.y); h[2] = f2bf(a0.z); h[3] = f2bf(a0.w);
        h[4] = f2bf(a1.x); h[5] = f2bf(a1.y); h[6] = f2bf(a1.z); h[7] = f2bf(a1.w);
        areg[s] = __builtin_bit_cast(s16x8, h);
    }
    f32x4 acc = {0.f, 0.f, 0.f, 0.f};
    const float* wb = W + (long long)(d0 + rr) * 2048 + kc0 + kq * 8;
#pragma unroll 4
    for (int s = 0; s < 16; ++s) {
        const float4 b0 = *(const float4*)(wb + s * 32);
        const float4 b1 = *(const float4*)(wb + s * 32 + 4);
        u16x8 h;
        h[0] = f2bf(b0.x); h[1] = f2bf(b0.y); h[2] = f2bf(b0.z); h[3] = f2bf(b0.w);
        h[4] = f2bf(b1.x); h[5] = f2bf(b1.y); h[6] = f2bf(b1.z); h[7] = f2bf(b1.w);
        acc = mfma16(areg[s], __builtin_bit_cast(s16x8, h), acc);
    }
    float* pb = part + ((long long)blockIdx.y * 16 + kq * 4) * 18432 + d0 + rr;
#pragma unroll
    for (int r = 0; r < 4; ++r) pb[(long long)r * 18432] = acc[r];
}

__global__ __launch_bounds__(256)
void zrkv_combine_kernel(const float* __restrict__ part, float* __restrict__ out)
{
    const int idx4 = blockIdx.x * 256 + threadIdx.x;
    const long long base = (long long)idx4 * 4;
    float4 s = {0.f, 0.f, 0.f, 0.f};
#pragma unroll
    for (int g = 0; g < 4; ++g) {
        const float4 v = *(const float4*)(part + (long long)g * 294912 + base);
        s.x += v.x; s.y += v.y; s.z += v.z; s.w += v.w;
    }
    *(float4*)(out + base) = s;
}

extern "C" void kernel_launch(void* const* d_in, const int* in_sizes, int n_in,
                              void* d_out, int out_size, void* d_ws, size_t ws_size,
                              hipStream_t stream)
{
    (void)in_sizes; (void)n_in; (void)out_size; (void)ws_size;
    const float* z_seq   = (const float*)d_in[0];
    const float* z_query = (const float*)d_in[1];
    const float* noise   = (const float*)d_in[2];
    const float* mm      = (const float*)d_in[3];
    const float* mlv     = (const float*)d_in[4];
    const float* wlv     = (const float*)d_in[5];
    const float* WM      = (const float*)d_in[6];
    float* out = (float*)d_out;   // [zr 32768 | Zrkv 294912 | dkl_M | dkl_w]

    char* wsb = (char*)d_ws;
    unsigned short* ztb  = (unsigned short*)(wsb);                  // 16 MB (B,S,C) bf16
    float*          wbuf = (float*)(wsb + (16LL << 20));            // 8 MB (B,S,K) f32
    unsigned short* nmmb = (unsigned short*)(wsb + (24LL << 20));   // 32 MB (B,K,C) bf16
    unsigned short* G3b  = (unsigned short*)(wsb + (56LL << 20));   // 8 MB (B,K,K) bf16
    float*          pool = (float*)(wsb + (64LL << 20));            // 16 MB phase pool
    float*          pZ   = (float*)(wsb + (80LL << 20));            // 4.5 MB zrkv partials
    float*          pR   = (float*)(wsb + (85LL << 20));            // 2 MB zret partials
    float*          vec  = (float*)(wsb + (87LL << 20));
    float* G1  = pool;
    float* r1a = pool + 262144;
    float* r1b = pool + 524288;
    float* t1  = pool + 786432;
    float* P1  = pool + 1048576;
    float* G2  = pool;
    float* r2a = pool + 1048576;
    float* r2b = pool + 2097152;
    float* t2  = pool + 3145728;
    float* Qb  = pool + 2097152;   // aliases r2b/t2 (dead when written)
    float* wmean    = vec;          // 8192
    float* uvec     = vec + 8192;   // 8192
    float* dklpart  = vec + 16384;  // 512
    float* vA       = vec + 24576;  // 8192
    float* vB       = vec + 32768;  // 8192

    prep_zt_kernel<<<4096, 256, 0, stream>>>(z_seq, noise, ztb);
    // G1 = mm @ mm^T (plain bf16)
    gemm_mfma<64,64,false,true,false,false,false,false,false><<<dim3(8,8,1),256,0,stream>>>(
        mm,2048,0, mm,2048,0, G1,512,0, nullptr,0, 1.f,0.f, 2048);
    r_init_kernel<<<1024,256,0,stream>>>(G1, r1a, 512, 262144);
    gemm_mfma<64,64,false,false,false,false,false,false,false><<<dim3(8,8,1),256,0,stream>>>(
        r1a,512,0, G1,512,0, t1,512,0, nullptr,0, 1.f,0.f, 512);
    gemm_mfma<64,64,false,false,false,false,false,false,false><<<dim3(8,8,1),256,0,stream>>>(
        t1,512,0, r1a,512,0, r1b,512,0, r1a,0, -1.f,2.f, 512);
    gemm_mfma<64,64,false,false,false,false,false,false,false><<<dim3(8,8,1),256,0,stream>>>(
        r1b,512,0, G1,512,0, t1,512,0, nullptr,0, 1.f,0.f, 512);
    gemm_mfma<64,64,false,false,false,false,false,false,false><<<dim3(8,8,1),256,0,stream>>>(
        t1,512,0, r1b,512,0, r1a,512,0, r1b,0, -1.f,2.f, 512);
    // P1 = mm^T @ r1 (2048,512,512)
    gemm_mfma<64,64,true,false,false,false,false,false,false><<<dim3(8,32,1),256,0,stream>>>(
        mm,2048,0, r1a,512,0, P1,512,0, nullptr,0, 1.f,0.f, 512);
    // w = zt_bf16 @ P1 (4096,512,2048)
    gemm_mfma<128,64,false,false,false,true,false,false,false><<<dim3(8,32,1),256,0,stream>>>(
        ztb,2048,0, P1,512,0, wbuf,512,0, nullptr,0, 1.f,0.f, 2048);
    // G2[b] = w[b] @ w[b]^T (batched)
    gemm_mfma<64,64,false,true,false,false,false,false,false><<<dim3(4,4,16),256,0,stream>>>(
        wbuf,512,131072, wbuf,512,131072, G2,256,65536, nullptr,0, 1.f,0.f, 512);
    r_init_kernel<<<4096,256,0,stream>>>(G2, r2a, 256, 1048576);
    gemm_mfma<64,64,false,false,false,false,false,false,false><<<dim3(4,4,16),256,0,stream>>>(
        r2a,256,65536, G2,256,65536, t2,256,65536, nullptr,0, 1.f,0.f, 256);
    gemm_mfma<64,64,false,false,false,false,false,false,false><<<dim3(4,4,16),256,0,stream>>>(
        t2,256,65536, r2a,256,65536, r2b,256,65536, r2a,65536, -1.f,2.f, 256);
    gemm_mfma<64,64,false,false,false,false,false,false,false><<<dim3(4,4,16),256,0,stream>>>(
        r2b,256,65536, G2,256,65536, t2,256,65536, nullptr,0, 1.f,0.f, 256);
    gemm_mfma<64,64,false,false,false,false,false,false,false><<<dim3(4,4,16),256,0,stream>>>(
        t2,256,65536, r2b,256,65536, r2a,256,65536, r2b,65536, -1.f,2.f, 256);
    // Qb[b] = w[b]^T @ r2[b] (512,256,256)
    gemm_mfma<64,64,true,false,false,false,false,false,false><<<dim3(4,8,16),256,0,stream>>>(
        wbuf,512,131072, r2a,256,65536, Qb,256,131072, nullptr,0, 1.f,0.f, 256);
    // nmm[b] = Qb[b] @ zt[b] -> bf16 (512,2048,256)
    gemm_mfma<128,128,false,false,false,false,true,true,false><<<dim3(16,4,16),256,0,stream>>>(
        Qb,256,131072, ztb,2048,524288, nmmb,2048,1048576, nullptr,0, 1.f,0.f, 256);
    // G3[b] = nmm[b] @ nmm[b]^T -> bf16, XCD-pinned (512,512,2048)
    gemm_mfma<128,128,false,true,false,true,true,true,true><<<dim3(256,1,1),256,0,stream>>>(
        nmmb,2048,1048576, nmmb,2048,1048576, G3b,512,262144, nullptr,0, 1.f,0.f, 2048);
    // fused u + dkl_M partials
    pass1_kernel<<<dim3(32,16),256,0,stream>>>(nmmb, z_query, mm, mlv, uvec, dklpart);
    // wmean = p3(G3) u  via 7 batched Krylov matvecs:
    //   p3: 8a -28a^2 L +56a^3 L^2 -70a^4 L^3 +56a^5 L^4 -28a^6 L^5 +8a^7 L^6 -a^8 L^7
    {
        const double a = (double)ALPHA;
        const float c0 = (float)(8.0 * a);
        const float c1 = (float)(-28.0 * a * a);
        const float c2 = (float)(56.0 * a * a * a);
        const float c3 = (float)(-70.0 * a * a * a * a);
        const float c4 = (float)(56.0 * a * a * a * a * a);
        const float c5 = (float)(-28.0 * a * a * a * a * a * a);
        const float c6 = (float)(8.0 * a * a * a * a * a * a * a);
        const float c7 = (float)(-1.0 * a * a * a * a * a * a * a * a);
        g3_matvec_kernel<<<dim3(32,16),256,0,stream>>>(G3b, uvec, vA, wmean, c1, c0, 1);
        g3_matvec_kernel<<<dim3(32,16),256,0,stream>>>(G3b, vA, vB, wmean, c2, 0.f, 0);
        g3_matvec_kernel<<<dim3(32,16),256,0,stream>>>(G3b, vB, vA, wmean, c3, 0.f, 0);
        g3_matvec_kernel<<<dim3(32,16),256,0,stream>>>(G3b, vA, vB, wmean, c4, 0.f, 0);
        g3_matvec_kernel<<<dim3(32,16),256,0,stream>>>(G3b, vB, vA, wmean, c5, 0.f, 0);
        g3_matvec_kernel<<<dim3(32,16),256,0,stream>>>(G3b, vA, vB, wmean, c6, 0.f, 0);
        g3_matvec_kernel<<<dim3(32,16),256,0,stream>>>(G3b, vB, vA, wmean, c7, 0.f, 0);
    }
    zret_part_kernel<<<dim3(16,16),256,0,stream>>>(nmmb, wmean, pR);
    epilogue_kernel<<<34,256,0,stream>>>(pR, dklpart, wmean, wlv, out);
    zrkv_mfma_kernel<<<dim3(288,4),256,0,stream>>>(WM, out, pZ);
    zrkv_combine_kernel<<<288,256,0,stream>>>(pZ, out + 32768);
}

// Round 5
// 255.260 us; speedup vs baseline: 11.7831x; 1.7788x over previous
//
#include <hip/hip_runtime.h>

#define ALPHA 5.0e-4f

typedef short s16x8 __attribute__((ext_vector_type(8)));
typedef unsigned short u16x8 __attribute__((ext_vector_type(8)));
typedef float f32x4 __attribute__((ext_vector_type(4)));

__device__ __forceinline__ unsigned short f2bf(float f) {
    unsigned int u = __builtin_bit_cast(unsigned int, f);
    u += 0x7fffu + ((u >> 16) & 1u);
    return (unsigned short)(u >> 16);
}
__device__ __forceinline__ float bf2f(unsigned short h) {
    return __builtin_bit_cast(float, (unsigned int)h << 16);
}
__device__ __forceinline__ f32x4 mfma16(s16x8 a, s16x8 b, f32x4 c) {
    return __builtin_amdgcn_mfma_f32_16x16x32_bf16(a, b, c, 0, 0, 0);
}

// ---------------------------------------------------------------------------
// Staging helpers -> LDS tile [ROWS][64 bf16], XOR-swizzled (slot ^= row&7).
// ---------------------------------------------------------------------------
template<int ROWS>
__device__ __forceinline__ void stage_kcontig(const float* __restrict__ src, int ld,
                                              unsigned short* __restrict__ lds, int tid)
{
#pragma unroll
    for (int it = 0; it < ROWS * 8 / 256; ++it) {
        const int g = tid + it * 256;
        const int row = g >> 3, s = g & 7;
        const float* p = src + (long long)row * ld + s * 8;
        const float4 x0 = *(const float4*)p;
        const float4 x1 = *(const float4*)(p + 4);
        u16x8 h;
        h[0] = f2bf(x0.x); h[1] = f2bf(x0.y); h[2] = f2bf(x0.z); h[3] = f2bf(x0.w);
        h[4] = f2bf(x1.x); h[5] = f2bf(x1.y); h[6] = f2bf(x1.z); h[7] = f2bf(x1.w);
        *(u16x8*)(lds + row * 64 + ((s ^ (row & 7)) << 3)) = h;
    }
}

template<int ROWS>
__device__ __forceinline__ void stage_kstrided(const float* __restrict__ src, int ld,
                                               unsigned short* __restrict__ lds, int tid)
{
    constexpr int KPT = ROWS * 64 / 256;
    const int m = tid % ROWS, kb = (tid / ROWS) * KPT;
#pragma unroll
    for (int j8 = 0; j8 < KPT / 8; ++j8) {
        u16x8 h;
#pragma unroll
        for (int j = 0; j < 8; ++j)
            h[j] = f2bf(src[(long long)(kb + j8 * 8 + j) * ld + m]);
        const int s = (kb >> 3) + j8;
        *(u16x8*)(lds + m * 64 + ((s ^ (m & 7)) << 3)) = h;
    }
}

template<int ROWS>
__device__ __forceinline__ void stage_kcontig_b(const unsigned short* __restrict__ src, int ld,
                                                unsigned short* __restrict__ lds, int tid)
{
#pragma unroll
    for (int it = 0; it < ROWS * 8 / 256; ++it) {
        const int g = tid + it * 256;
        const int row = g >> 3, s = g & 7;
        const u16x8 h = *(const u16x8*)(src + (long long)row * ld + s * 8);
        *(u16x8*)(lds + row * 64 + ((s ^ (row & 7)) << 3)) = h;
    }
}

template<int ROWS>
__device__ __forceinline__ void stage_kstrided_b(const unsigned short* __restrict__ src, int ld,
                                                 unsigned short* __restrict__ lds, int tid)
{
    constexpr int KPT = ROWS * 64 / 256;
    const int m = tid % ROWS, kb = (tid / ROWS) * KPT;
#pragma unroll
    for (int j8 = 0; j8 < KPT / 8; ++j8) {
        u16x8 h;
#pragma unroll
        for (int j = 0; j < 8; ++j)
            h[j] = src[(long long)(kb + j8 * 8 + j) * ld + m];
        const int s = (kb >> 3) + j8;
        *(u16x8*)(lds + m * 64 + ((s ^ (m & 7)) << 3)) = h;
    }
}

// ---------------------------------------------------------------------------
// Unified MFMA GEMM:  D = alpha*op(A)@op(B) + beta*Cin
//   ABF/BBF: operand is bf16 in global.  OBF: store bf16.
//   OT: store bf16 TRANSPOSED per 256-row batches: D[(row>>8)*sD + col*ldd + (row&255)]
//   CINT: Cin is transposed, read Cin[col*sC + row].
// ---------------------------------------------------------------------------
template<int BM, int BN, bool TA, bool TB, bool ABF, bool BBF, bool OBF,
         bool OT = false, bool CINT = false>
__global__ __launch_bounds__(256)
void gemm_mfma(const void* __restrict__ Av, int lda, long long sA,
               const void* __restrict__ Bv, int ldb, long long sB,
               void* __restrict__ Dv, int ldd, long long sD,
               const float* __restrict__ Cin, long long sC,
               float alpha, float beta, int Kd)
{
    constexpr int TWM = BM / 2, TWN = BN / 2;
    constexpr int FM = TWM / 16, FN = TWN / 16;
    __shared__ unsigned short As[BM * 64];
    __shared__ unsigned short Bs[BN * 64];

    const int bx = blockIdx.x, by = blockIdx.y, bz = blockIdx.z;
    const int tid = threadIdx.x;
    const int lane = tid & 63, w = tid >> 6;
    const int wm = w >> 1, wn = w & 1;
    const int lrow = lane & 15, lk = lane >> 4;
    const int m0 = by * BM, n0 = bx * BN;

    f32x4 acc[FM][FN];
#pragma unroll
    for (int i = 0; i < FM; ++i)
#pragma unroll
        for (int j = 0; j < FN; ++j) acc[i][j] = (f32x4){0.f, 0.f, 0.f, 0.f};

    for (int k0 = 0; k0 < Kd; k0 += 64) {
        if (ABF) {
            const unsigned short* Ab = (const unsigned short*)Av + (long long)bz * sA;
            if (!TA) stage_kcontig_b<BM>(Ab + (long long)m0 * lda + k0, lda, As, tid);
            else     stage_kstrided_b<BM>(Ab + (long long)k0 * lda + m0, lda, As, tid);
        } else {
            const float* Ab = (const float*)Av + (long long)bz * sA;
            if (!TA) stage_kcontig<BM>(Ab + (long long)m0 * lda + k0, lda, As, tid);
            else     stage_kstrided<BM>(Ab + (long long)k0 * lda + m0, lda, As, tid);
        }
        if (BBF) {
            const unsigned short* Bb = (const unsigned short*)Bv + (long long)bz * sB;
            if (TB)  stage_kcontig_b<BN>(Bb + (long long)n0 * ldb + k0, ldb, Bs, tid);
            else     stage_kstrided_b<BN>(Bb + (long long)k0 * ldb + n0, ldb, Bs, tid);
        } else {
            const float* Bb = (const float*)Bv + (long long)bz * sB;
            if (TB)  stage_kcontig<BN>(Bb + (long long)n0 * ldb + k0, ldb, Bs, tid);
            else     stage_kstrided<BN>(Bb + (long long)k0 * ldb + n0, ldb, Bs, tid);
        }
        __syncthreads();
#pragma unroll
        for (int kk = 0; kk < 2; ++kk) {
            s16x8 ah[FM], bh[FN];
#pragma unroll
            for (int i = 0; i < FM; ++i) {
                const int row = wm * TWM + i * 16 + lrow;
                const int s = kk * 4 + lk;
                ah[i] = *(const s16x8*)(As + row * 64 + ((s ^ (row & 7)) << 3));
            }
#pragma unroll
            for (int j = 0; j < FN; ++j) {
                const int col = wn * TWN + j * 16 + lrow;
                const int s = kk * 4 + lk;
                bh[j] = *(const s16x8*)(Bs + col * 64 + ((s ^ (col & 7)) << 3));
            }
#pragma unroll
            for (int i = 0; i < FM; ++i)
#pragma unroll
                for (int j = 0; j < FN; ++j)
                    acc[i][j] = mfma16(ah[i], bh[j], acc[i][j]);
        }
        __syncthreads();
    }

    const float* Cb = Cin ? (Cin + (long long)bz * sC) : nullptr;
#pragma unroll
    for (int i = 0; i < FM; ++i)
#pragma unroll
        for (int j = 0; j < FN; ++j) {
            const int col = n0 + wn * TWN + j * 16 + lrow;
#pragma unroll
            for (int r = 0; r < 4; ++r) {
                const int row = m0 + wm * TWM + i * 16 + lk * 4 + r;
                float v = alpha * acc[i][j][r];
                if (Cb) {
                    const float cv = CINT ? Cin[(long long)col * sC + row]
                                          : Cb[(long long)row * ldd + col];
                    v = fmaf(beta, cv, v);
                }
                if (OT) {
                    ((unsigned short*)Dv)[(long long)(row >> 8) * sD +
                                          (long long)col * ldd + (row & 255)] = f2bf(v);
                } else if (OBF) {
                    ((unsigned short*)Dv + (long long)bz * sD)[(long long)row * ldd + col] = f2bf(v);
                } else {
                    ((float*)Dv + (long long)bz * sD)[(long long)row * ldd + col] = v;
                }
            }
        }
}

// zt_bf16[b][s][c] = bf16(z_seq[s][b][c] + 0.01*noise[s][b][c])
__global__ __launch_bounds__(256)
void prep_zt_kernel(const float* __restrict__ zs, const float* __restrict__ no,
                    unsigned short* __restrict__ ztb)
{
    const long long i8 = (long long)blockIdx.x * 256 + threadIdx.x;
    const long long c8 = i8 & 255;
    const long long bs = i8 >> 8;
    const long long b = bs >> 8, sI = bs & 255;
    const long long in = (sI * 16 + b) * 2048 + c8 * 8;
    const float4 z0 = *(const float4*)(zs + in);
    const float4 z1 = *(const float4*)(zs + in + 4);
    const float4 n0 = *(const float4*)(no + in);
    const float4 n1 = *(const float4*)(no + in + 4);
    u16x8 o;
    o[0] = f2bf(fmaf(0.01f, n0.x, z0.x)); o[1] = f2bf(fmaf(0.01f, n0.y, z0.y));
    o[2] = f2bf(fmaf(0.01f, n0.z, z0.z)); o[3] = f2bf(fmaf(0.01f, n0.w, z0.w));
    o[4] = f2bf(fmaf(0.01f, n1.x, z1.x)); o[5] = f2bf(fmaf(0.01f, n1.y, z1.y));
    o[6] = f2bf(fmaf(0.01f, n1.z, z1.z)); o[7] = f2bf(fmaf(0.01f, n1.w, z1.w));
    *(u16x8*)(ztb + i8 * 8) = o;
}

// Fused pass over nmm_bf16: wmean[b,k] = 8a * <nmm[b,k,:], zq[b,:]>, dkl_M partials.
__global__ __launch_bounds__(256)
void pass1_kernel(const unsigned short* __restrict__ nmmb, const float* __restrict__ zq,
                  const float* __restrict__ mm, const float* __restrict__ mlv,
                  float* __restrict__ wmean, float* __restrict__ dklpart)
{
    const int b = blockIdx.y, k0 = blockIdx.x * 16;
    const int t = threadIdx.x, row = t >> 4, c16 = t & 15;
    __shared__ float zqs[2048];
    __shared__ float red[256];
    for (int c = t; c < 2048; c += 256) zqs[c] = zq[b * 2048 + c];
    __syncthreads();
    const int k = k0 + row;
    const unsigned short* np = nmmb + (long long)b * 1048576 + (long long)k * 2048;
    const float* mp = mm + (long long)k * 2048;
    float ua = 0.f, da = 0.f;
#pragma unroll 4
    for (int j = 0; j < 16; ++j) {
        const int c = c16 * 8 + j * 128;
        const u16x8 nv = *(const u16x8*)(np + c);
        const float4 m0 = *(const float4*)(mp + c);
        const float4 m1 = *(const float4*)(mp + c + 4);
        const float mf[8] = {m0.x, m0.y, m0.z, m0.w, m1.x, m1.y, m1.z, m1.w};
#pragma unroll
        for (int jj = 0; jj < 8; ++jj) {
            const float nf = bf2f(nv[jj]);
            ua = fmaf(nf, zqs[c + jj], ua);
            const float d = nf - mf[jj];
            da = fmaf(d, d, da);
        }
    }
    for (int off = 8; off; off >>= 1) ua += __shfl_down(ua, off, 16);
    if (c16 == 0) wmean[b * 512 + k] = (8.0f * ALPHA) * ua;
    da *= 1.0f / (expf(mlv[k]) + 1e-6f);
    red[t] = da; __syncthreads();
    for (int st = 128; st > 0; st >>= 1) { if (t < st) red[t] += red[t + st]; __syncthreads(); }
    if (t == 0) dklpart[blockIdx.y * 32 + blockIdx.x] = red[0];
}

// zret partial over k-range 32: pR[ksp][b][c] = sum_k wmean*nmm
__global__ __launch_bounds__(256)
void zret_part_kernel(const unsigned short* __restrict__ nmmb, const float* __restrict__ wmean,
                      float* __restrict__ pR)
{
    const int b = blockIdx.y, k0 = blockIdx.x * 32, t = threadIdx.x;
    __shared__ float wms[32];
    if (t < 32) wms[t] = wmean[b * 512 + k0 + t];
    __syncthreads();
    const int c = t * 8;
    const unsigned short* np = nmmb + (long long)b * 1048576 + (long long)k0 * 2048 + c;
    float a[8] = {0.f, 0.f, 0.f, 0.f, 0.f, 0.f, 0.f, 0.f};
    for (int k = 0; k < 32; ++k) {
        const u16x8 nv = *(const u16x8*)(np + (long long)k * 2048);
        const float wv = wms[k];
#pragma unroll
        for (int jj = 0; jj < 8; ++jj) a[jj] = fmaf(wv, bf2f(nv[jj]), a[jj]);
    }
    float* o = pR + ((long long)blockIdx.x * 16 + b) * 2048 + c;
    *(float4*)o = (float4){a[0], a[1], a[2], a[3]};
    *(float4*)(o + 4) = (float4){a[4], a[5], a[6], a[7]};
}

// Fused epilogue: blocks 0..31 zret combine; block 32 dkl_M final; block 33 dkl_w.
__global__ __launch_bounds__(256)
void epilogue_kernel(const float* __restrict__ pR, const float* __restrict__ dklpart,
                     const float* __restrict__ wmean, const float* __restrict__ wlv,
                     float* __restrict__ out)
{
    const int blk = blockIdx.x, t = threadIdx.x;
    if (blk < 32) {
        const int idx4 = blk * 256 + t;
        const int b = idx4 >> 9, c = (idx4 & 511) * 4;
        float4 s = {0.f, 0.f, 0.f, 0.f};
#pragma unroll
        for (int g = 0; g < 16; ++g) {
            const float4 v = *(const float4*)(pR + ((long long)g * 16 + b) * 2048 + c);
            s.x += v.x; s.y += v.y; s.z += v.z; s.w += v.w;
        }
        *(float4*)(out + (long long)b * 2048 + c) = s;
    } else if (blk == 32) {
        __shared__ float red[256];
        float s = 0.f;
        for (int i = t; i < 512; i += 256) s += dklpart[i];
        red[t] = s; __syncthreads();
        for (int st = 128; st > 0; st >>= 1) { if (t < st) red[t] += red[t + st]; __syncthreads(); }
        if (t == 0) out[327680] = red[0] * (1.0f / 16.0f);
    } else {
        __shared__ float red[256];
        float s = 0.f;
        for (int i = t; i < 16 * 512; i += 256) { const float v = wmean[i]; s += v * v; }
        red[t] = s; __syncthreads();
        for (int st = 128; st > 0; st >>= 1) { if (t < st) red[t] += red[t + st]; __syncthreads(); }
        if (t == 0) {
            const float l = wlv[0];
            out[327681] = 0.5f * (red[0] + 8192.0f * (expf(l) - 1.0f - l));
        }
    }
}

// Z_r_kv partials: MFMA streaming over W (M=16 b, N=18432 d, K=2048, Ksplit 4)
__global__ __launch_bounds__(256)
void zrkv_mfma_kernel(const float* __restrict__ W, const float* __restrict__ zr,
                      float* __restrict__ part)
{
    const int tid = threadIdx.x, lane = tid & 63, w = tid >> 6;
    const int d0 = blockIdx.x * 64 + w * 16;
    const int kc0 = blockIdx.y * 512;
    const int rr = lane & 15, kq = lane >> 4;
    s16x8 areg[16];
    const float* zb = zr + rr * 2048 + kc0 + kq * 8;
#pragma unroll
    for (int s = 0; s < 16; ++s) {
        const float4 a0 = *(const float4*)(zb + s * 32);
        const float4 a1 = *(const float4*)(zb + s * 32 + 4);
        u16x8 h;
        h[0] = f2bf(a0.x); h[1] = f2bf(a0.y); h[2] = f2bf(a0.z); h[3] = f2bf(a0.w);
        h[4] = f2bf(a1.x); h[5] = f2bf(a1.y); h[6] = f2bf(a1.z); h[7] = f2bf(a1.w);
        areg[s] = __builtin_bit_cast(s16x8, h);
    }
    f32x4 acc = {0.f, 0.f, 0.f, 0.f};
    const float* wb = W + (long long)(d0 + rr) * 2048 + kc0 + kq * 8;
#pragma unroll 4
    for (int s = 0; s < 16; ++s) {
        const float4 b0 = *(const float4*)(wb + s * 32);
        const float4 b1 = *(const float4*)(wb + s * 32 + 4);
        u16x8 h;
        h[0] = f2bf(b0.x); h[1] = f2bf(b0.y); h[2] = f2bf(b0.z); h[3] = f2bf(b0.w);
        h[4] = f2bf(b1.x); h[5] = f2bf(b1.y); h[6] = f2bf(b1.z); h[7] = f2bf(b1.w);
        acc = mfma16(areg[s], __builtin_bit_cast(s16x8, h), acc);
    }
    float* pb = part + ((long long)blockIdx.y * 16 + kq * 4) * 18432 + d0 + rr;
#pragma unroll
    for (int r = 0; r < 4; ++r) pb[(long long)r * 18432] = acc[r];
}

__global__ __launch_bounds__(256)
void zrkv_combine_kernel(const float* __restrict__ part, float* __restrict__ out)
{
    const int idx4 = blockIdx.x * 256 + threadIdx.x;
    const long long base = (long long)idx4 * 4;
    float4 s = {0.f, 0.f, 0.f, 0.f};
#pragma unroll
    for (int g = 0; g < 4; ++g) {
        const float4 v = *(const float4*)(part + (long long)g * 294912 + base);
        s.x += v.x; s.y += v.y; s.z += v.z; s.w += v.w;
    }
    *(float4*)(out + base) = s;
}

extern "C" void kernel_launch(void* const* d_in, const int* in_sizes, int n_in,
                              void* d_out, int out_size, void* d_ws, size_t ws_size,
                              hipStream_t stream)
{
    (void)in_sizes; (void)n_in; (void)out_size; (void)ws_size;
    const float* z_seq   = (const float*)d_in[0];
    const float* z_query = (const float*)d_in[1];
    const float* noise   = (const float*)d_in[2];
    const float* mm      = (const float*)d_in[3];
    const float* mlv     = (const float*)d_in[4];
    const float* wlv     = (const float*)d_in[5];
    const float* WM      = (const float*)d_in[6];
    float* out = (float*)d_out;   // [zr 32768 | Zrkv 294912 | dkl_M | dkl_w]

    char* wsb = (char*)d_ws;
    unsigned short* ztb  = (unsigned short*)(wsb);                  // 16 MB (B,S,C) bf16
    unsigned short* wTb  = (unsigned short*)(wsb + (16LL << 20));   // 4 MB (B,K,S) bf16
    unsigned short* nmmb = (unsigned short*)(wsb + (24LL << 20));   // 32 MB (B,K,C) bf16
    float*          G1   = (float*)(wsb + (64LL << 20));            // 1 MB (K,K)
    float*          P1   = (float*)(wsb + (66LL << 20));            // 4 MB (C,K)
    float*          pZ   = (float*)(wsb + (80LL << 20));            // 4.5 MB zrkv partials
    float*          pR   = (float*)(wsb + (85LL << 20));            // 2 MB zret partials
    float*          vec  = (float*)(wsb + (87LL << 20));
    float* wmean    = vec;          // 8192
    float* dklpart  = vec + 8192;   // 512

    // 1. zt (bf16), transposed + noise
    prep_zt_kernel<<<4096, 256, 0, stream>>>(z_seq, noise, ztb);
    // 2. G1 = mm @ mm^T   (512,512,2048)
    gemm_mfma<64,64,false,true,false,false,false><<<dim3(8,8,1),256,0,stream>>>(
        mm,2048,0, mm,2048,0, G1,512,0, nullptr,0, 1.f,0.f, 2048);
    // 3. P1 = 8a*mm^T - 28a^2*(mm^T @ G1)   (2048,512,512), Cin = mm transposed
    gemm_mfma<64,64,true,false,false,false,false,false,true><<<dim3(8,32,1),256,0,stream>>>(
        mm,2048,0, G1,512,0, P1,512,0, mm,2048,
        -28.0f*ALPHA*ALPHA, 8.0f*ALPHA, 512);
    // 4. wT[b][k][s] = (zt @ P1)^T, stored bf16 transposed (4096,512,2048)
    gemm_mfma<128,128,false,false,true,false,true,true,false><<<dim3(4,32,1),256,0,stream>>>(
        ztb,2048,0, P1,512,0, wTb,256,131072, nullptr,0, 1.f,0.f, 2048);
    // 5. nmm[b] = 8a * wT[b] @ zt[b]  -> bf16  (512,2048,256)
    gemm_mfma<128,128,false,false,true,true,true><<<dim3(16,4,16),256,0,stream>>>(
        wTb,256,131072, ztb,2048,524288, nmmb,2048,1048576, nullptr,0,
        8.0f*ALPHA, 0.f, 256);
    // 6. fused: wmean = 8a * (nmm @ zq), dkl_M partials
    pass1_kernel<<<dim3(32,16),256,0,stream>>>(nmmb, z_query, mm, mlv, wmean, dklpart);
    // 7-8. z_retrieved (k-split + combine) and scalar outputs
    zret_part_kernel<<<dim3(16,16),256,0,stream>>>(nmmb, wmean, pR);
    epilogue_kernel<<<34,256,0,stream>>>(pR, dklpart, wmean, wlv, out);
    // 9-10. Z_r_kv = zr @ W^T (K-split MFMA stream + combine)
    zrkv_mfma_kernel<<<dim3(288,4),256,0,stream>>>(WM, out, pZ);
    zrkv_combine_kernel<<<288,256,0,stream>>>(pZ, out + 32768);
}